// Round 2
// baseline (3265.839 us; speedup 1.0000x reference)
//
#include <hip/hip_runtime.h>

#define DEVINL __device__ __forceinline__

constexpr int NUSER = 50000;
constexpr int NTOT  = 100000;   // NUM_USER + NUM_ITEM
constexpr int DF    = 128;
constexpr int D     = 64;
constexpr int NE    = 2000000;
constexpr int SCANB = 256;
constexpr int NBLK  = (NTOT + SCANB - 1) / SCANB;  // 391

DEVINL float leaky(float v) { return v > 0.f ? v : 0.01f * v; }

// ---------------------------------------------------------------------------
__global__ __launch_bounds__(256) void k_zero(int* __restrict__ p, int n) {
  int i = blockIdx.x * blockDim.x + threadIdx.x;
  if (i < n) p[i] = 0;
}

// ---------------------------------------------------------------------------
// x[0:NUSER] = preference; x[NUSER:] = features @ mlp_w.T + mlp_b; then
// row-normalize. One wave per row.
__global__ __launch_bounds__(256) void k_init(
    const float* __restrict__ feat, const float* __restrict__ pref,
    const float* __restrict__ mlp_w, const float* __restrict__ mlp_b,
    float* __restrict__ x) {
  int wid  = (blockIdx.x * blockDim.x + threadIdx.x) >> 6;
  int lane = threadIdx.x & 63;
  if (wid >= NTOT) return;
  float v;
  if (wid < NUSER) {
    v = pref[wid * D + lane];
  } else {
    int it = wid - NUSER;
    const float4* fr = (const float4*)(feat + (size_t)it * DF);
    const float4* wr = (const float4*)(mlp_w + (size_t)lane * DF);
    float acc = 0.f;
#pragma unroll
    for (int k = 0; k < DF / 4; ++k) {
      float4 a = fr[k];  // wave-uniform address -> L1 broadcast
      float4 b = wr[k];
      acc += a.x * b.x + a.y * b.y + a.z * b.z + a.w * b.w;
    }
    v = acc + mlp_b[lane];
  }
  float ss = v * v;
#pragma unroll
  for (int o = 32; o; o >>= 1) ss += __shfl_xor(ss, o);
  float inv = 1.0f / fmaxf(sqrtf(ss), 1e-12f);
  x[(size_t)wid * D + lane] = v * inv;
}

// ---------------------------------------------------------------------------
// CSR build: histogram of dst, 3-phase exclusive scan, cursor scatter.
__global__ void k_hist(const int* __restrict__ dst, int* __restrict__ deg) {
  int e = blockIdx.x * blockDim.x + threadIdx.x;
  if (e < NE) atomicAdd(&deg[dst[e]], 1);
}

__global__ void k_scan1(const int* __restrict__ deg, int* __restrict__ bsum) {
  __shared__ int s[SCANB];
  int i = blockIdx.x * SCANB + threadIdx.x;
  s[threadIdx.x] = (i < NTOT) ? deg[i] : 0;
  __syncthreads();
  for (int o = SCANB / 2; o; o >>= 1) {
    if (threadIdx.x < o) s[threadIdx.x] += s[threadIdx.x + o];
    __syncthreads();
  }
  if (threadIdx.x == 0) bsum[blockIdx.x] = s[0];
}

__global__ void k_scan2(int* __restrict__ bsum) {  // single block of 512
  __shared__ int s[512];
  int t = threadIdx.x;
  int v = (t < NBLK) ? bsum[t] : 0;
  s[t] = v;
  __syncthreads();
  for (int o = 1; o < 512; o <<= 1) {
    int a = (t >= o) ? s[t - o] : 0;
    __syncthreads();
    s[t] += a;
    __syncthreads();
  }
  if (t < NBLK) bsum[t] = s[t] - v;  // exclusive
}

__global__ void k_scan3(const int* __restrict__ deg, const int* __restrict__ bsum,
                        int* __restrict__ rowptr, int* __restrict__ cursor) {
  __shared__ int s[SCANB];
  int t = threadIdx.x;
  int i = blockIdx.x * SCANB + t;
  int v = (i < NTOT) ? deg[i] : 0;
  s[t] = v;
  __syncthreads();
  for (int o = 1; o < SCANB; o <<= 1) {
    int a = (t >= o) ? s[t - o] : 0;
    __syncthreads();
    s[t] += a;
    __syncthreads();
  }
  if (i < NTOT) {
    int ex = s[t] - v + bsum[blockIdx.x];
    rowptr[i] = ex;
    cursor[i] = ex;
  }
  if (i == 0) rowptr[NTOT] = NE;
}

__global__ void k_scatter(const int* __restrict__ src, const int* __restrict__ dst,
                          int* __restrict__ cursor, int* __restrict__ csr) {
  int e = blockIdx.x * blockDim.x + threadIdx.x;
  if (e < NE) {
    int p = atomicAdd(&cursor[dst[e]], 1);
    csr[p] = src[e];
  }
}

// ---------------------------------------------------------------------------
// agg[n] = sum over incoming edges of x[src]. One wave per node, no atomics.
__global__ __launch_bounds__(256) void k_agg(
    const float* __restrict__ x, const int* __restrict__ rowptr,
    const int* __restrict__ csr, float* __restrict__ agg) {
  int wid  = (blockIdx.x * blockDim.x + threadIdx.x) >> 6;
  int lane = threadIdx.x & 63;
  if (wid >= NTOT) return;
  int e0 = rowptr[wid], e1 = rowptr[wid + 1];
  float acc = 0.f;
  for (int e = e0; e < e1; ++e) {
    int s = csr[e];  // wave-uniform
    acc += x[(size_t)s * D + lane];
  }
  agg[(size_t)wid * D + lane] = acc;
}

// ---------------------------------------------------------------------------
// hOut[r]  = leaky(aggIn[r] @ conv_w)            (conv_w is [k][j], [in,out])
// xhOut[r] = leaky(xIn[r] @ lin_w.T + lin_b)     (lin_w is [j][k], [out,in])
// May run IN-PLACE (hOut==aggIn, xhOut==xIn): each row is owned by exactly
// one wave, and the stores depend on all the row's loads through registers,
// so dataflow ordering makes the overwrite safe.
__global__ __launch_bounds__(256) void k_hx(
    const float* __restrict__ aggIn, const float* __restrict__ xIn,
    const float* __restrict__ convw, const float* __restrict__ linw,
    const float* __restrict__ linb,
    float* __restrict__ hOut, float* __restrict__ xhOut) {
  int lane = threadIdx.x & 63;
  float wc[D], wl[D];
#pragma unroll
  for (int k = 0; k < D; ++k) wc[k] = convw[k * D + lane];  // column `lane`
  const float4* lr = (const float4*)(linw + (size_t)lane * D);
#pragma unroll
  for (int k = 0; k < D / 4; ++k) {
    float4 t = lr[k];
    wl[4 * k] = t.x; wl[4 * k + 1] = t.y; wl[4 * k + 2] = t.z; wl[4 * k + 3] = t.w;
  }
  float bias = linb[lane];
  int nw   = (gridDim.x * blockDim.x) >> 6;
  int wid0 = (blockIdx.x * blockDim.x + threadIdx.x) >> 6;
  for (int r = wid0; r < NTOT; r += nw) {
    const float4* ar = (const float4*)(aggIn + (size_t)r * D);
    const float4* xr = (const float4*)(xIn + (size_t)r * D);
    float h = 0.f, xh = bias;
#pragma unroll
    for (int k = 0; k < D / 4; ++k) {
      float4 a = ar[k];  // wave-uniform -> L1 broadcast
      float4 b = xr[k];
      h  += a.x * wc[4 * k] + a.y * wc[4 * k + 1] + a.z * wc[4 * k + 2] + a.w * wc[4 * k + 3];
      xh += b.x * wl[4 * k] + b.y * wl[4 * k + 1] + b.z * wl[4 * k + 2] + b.w * wl[4 * k + 3];
    }
    hOut[(size_t)r * D + lane]  = leaky(h);
    xhOut[(size_t)r * D + lane] = leaky(xh);
  }
}

// out[r] = (leaky?) (h[r] @ gw[:, :64].T + xh[r] @ gw[:, 64:].T + g_b)
// gw is [j][k] with k in [0,128). out may alias h (read-before-write via
// register dataflow, one wave per row).
__global__ __launch_bounds__(256) void k_g(
    const float* __restrict__ h, const float* __restrict__ xh,
    const float* __restrict__ gw, const float* __restrict__ gb,
    float* __restrict__ out, int do_leaky) {
  int lane = threadIdx.x & 63;
  float whr[D], wxr[D];
  const float4* g0 = (const float4*)(gw + (size_t)lane * 2 * D);
  const float4* g1 = (const float4*)(gw + (size_t)lane * 2 * D + D);
#pragma unroll
  for (int k = 0; k < D / 4; ++k) {
    float4 t0 = g0[k];
    whr[4 * k] = t0.x; whr[4 * k + 1] = t0.y; whr[4 * k + 2] = t0.z; whr[4 * k + 3] = t0.w;
    float4 t1 = g1[k];
    wxr[4 * k] = t1.x; wxr[4 * k + 1] = t1.y; wxr[4 * k + 2] = t1.z; wxr[4 * k + 3] = t1.w;
  }
  float bias = gb[lane];
  int nw   = (gridDim.x * blockDim.x) >> 6;
  int wid0 = (blockIdx.x * blockDim.x + threadIdx.x) >> 6;
  for (int r = wid0; r < NTOT; r += nw) {
    const float4* hr = (const float4*)(h + (size_t)r * D);
    const float4* xr = (const float4*)(xh + (size_t)r * D);
    float acc = bias;
#pragma unroll
    for (int k = 0; k < D / 4; ++k) {
      float4 a = hr[k];
      float4 b = xr[k];
      acc += a.x * whr[4 * k] + a.y * whr[4 * k + 1] + a.z * whr[4 * k + 2] + a.w * whr[4 * k + 3];
      acc += b.x * wxr[4 * k] + b.y * wxr[4 * k + 1] + b.z * wxr[4 * k + 2] + b.w * wxr[4 * k + 3];
    }
    if (do_leaky) acc = leaky(acc);
    out[(size_t)r * D + lane] = acc;
  }
}

// ---------------------------------------------------------------------------
extern "C" void kernel_launch(void* const* d_in, const int* in_sizes, int n_in,
                              void* d_out, int out_size, void* d_ws, size_t ws_size,
                              hipStream_t stream) {
  const float* features = (const float*)d_in[0];
  const int*   ei       = (const int*)d_in[1];
  const float* pref     = (const float*)d_in[2];
  const float* mlp_w    = (const float*)d_in[3];
  const float* mlp_b    = (const float*)d_in[4];
  const float* conv_w[5]; const float* lin_w[5]; const float* lin_b[5];
  const float* g_w[5];    const float* g_b[5];
  if (n_in >= 30) {
    // 30-leaf layout: each list element is its own input
    for (int i = 0; i < 5; ++i) {
      conv_w[i] = (const float*)d_in[5 + i];
      lin_w[i]  = (const float*)d_in[10 + i];
      lin_b[i]  = (const float*)d_in[15 + i];
      g_w[i]    = (const float*)d_in[20 + i];
      g_b[i]    = (const float*)d_in[25 + i];
    }
  } else {
    // 10-buffer layout: each list concatenated into one buffer
    const float* cw = (const float*)d_in[5];
    const float* lw = (const float*)d_in[6];
    const float* lb = (const float*)d_in[7];
    const float* gw = (const float*)d_in[8];
    const float* gb = (const float*)d_in[9];
    for (int i = 0; i < 5; ++i) {
      conv_w[i] = cw + (size_t)i * D * D;
      lin_w[i]  = lw + (size_t)i * D * D;
      lin_b[i]  = lb + (size_t)i * D;
      g_w[i]    = gw + (size_t)i * D * 2 * D;
      g_b[i]    = gb + (size_t)i * D;
    }
  }
  const int* e_src = ei;
  const int* e_dst = ei + NE;

  char* p = (char*)d_ws;
  float* xa     = (float*)p; p += (size_t)NTOT * D * 4;        // 25.6 MB
  float* xb     = (float*)p; p += (size_t)NTOT * D * 4;        // 25.6 MB
  float* agg    = (float*)p; p += (size_t)NTOT * D * 4;        // 25.6 MB
  int*   csr    = (int*)p;   p += (size_t)NE * 4;              // 8 MB
  int*   deg    = (int*)p;   p += (size_t)NTOT * 4;
  int*   rowptr = (int*)p;   p += (size_t)(NTOT + 4) * 4;
  int*   cursor = (int*)p;   p += (size_t)NTOT * 4;
  int*   bsum   = (int*)p;   p += 1024 * 4;
  // total ~86.4 MB

  float* mu     = (float*)d_out;
  float* logvar = (float*)d_out + (size_t)NTOT * D;

  const int WPB = 4;  // waves per block (block = 256)
  int grid_rows  = (NTOT + WPB - 1) / WPB;        // 25000
  int grid_edges = (NE + 255) / 256;              // 7813
  int grid_dense = 1792;                          // grid-stride dense kernels

  // x = normalize(concat(preference, features @ mlp_w.T + mlp_b))
  k_init<<<grid_rows, 256, 0, stream>>>(features, pref, mlp_w, mlp_b, xa);

  // CSR by dst (rebuilt every call; deterministic work)
  k_zero<<<(NTOT + 255) / 256, 256, 0, stream>>>(deg, NTOT);
  k_hist<<<grid_edges, 256, 0, stream>>>(e_dst, deg);
  k_scan1<<<NBLK, SCANB, 0, stream>>>(deg, bsum);
  k_scan2<<<1, 512, 0, stream>>>(bsum);
  k_scan3<<<NBLK, SCANB, 0, stream>>>(deg, bsum, rowptr, cursor);
  k_scatter<<<grid_edges, 256, 0, stream>>>(e_src, e_dst, cursor, csr);

  for (int i = 0; i < 3; ++i) {
    k_agg<<<grid_rows, 256, 0, stream>>>(xa, rowptr, csr, agg);
    // in-place: h over agg, xh over xa
    k_hx<<<grid_dense, 256, 0, stream>>>(agg, xa, conv_w[i], lin_w[i], lin_b[i], agg, xa);
    k_g<<<grid_dense, 256, 0, stream>>>(agg, xa, g_w[i], g_b[i], xb, 1);
    float* t = xa; xa = xb; xb = t;
  }

  // Heads share one aggregation of the final x. Head k_hx writes to separate
  // buffers so agg/xa survive for the second head.
  k_agg<<<grid_rows, 256, 0, stream>>>(xa, rowptr, csr, agg);
  k_hx<<<grid_dense, 256, 0, stream>>>(agg, xa, conv_w[3], lin_w[3], lin_b[3], mu, xb);
  k_g<<<grid_dense, 256, 0, stream>>>(mu, xb, g_w[3], g_b[3], mu, 0);
  k_hx<<<grid_dense, 256, 0, stream>>>(agg, xa, conv_w[4], lin_w[4], lin_b[4], logvar, xb);
  k_g<<<grid_dense, 256, 0, stream>>>(logvar, xb, g_w[4], g_b[4], logvar, 0);
}

// Round 3
// 2708.451 us; speedup vs baseline: 1.2058x; 1.2058x over previous
//
#include <hip/hip_runtime.h>

#define DEVINL __device__ __forceinline__

constexpr int NUSER = 50000;
constexpr int NTOT  = 100000;   // NUM_USER + NUM_ITEM
constexpr int DF    = 128;
constexpr int D     = 64;
constexpr int NE    = 2000000;
constexpr int SCANB = 256;
constexpr int NBLK  = (NTOT + SCANB - 1) / SCANB;  // 391

DEVINL float leaky(float v) { return v > 0.f ? v : 0.01f * v; }

// ---------------------------------------------------------------------------
__global__ __launch_bounds__(256) void k_zero(int* __restrict__ p, int n) {
  int i = blockIdx.x * blockDim.x + threadIdx.x;
  if (i < n) p[i] = 0;
}

// ---------------------------------------------------------------------------
// x[0:NUSER] = preference; x[NUSER:] = features @ mlp_w.T + mlp_b; then
// row-normalize. Grid-stride, one wave per row, mlp_w row held in VGPRs
// (lane = output column j, weights mlp_w[j][0:128] = 128 regs).
__global__ __launch_bounds__(256) void k_init(
    const float* __restrict__ feat, const float* __restrict__ pref,
    const float* __restrict__ mlp_w, const float* __restrict__ mlp_b,
    float* __restrict__ x) {
  int lane = threadIdx.x & 63;
  float wr[DF];
  const float4* wp = (const float4*)(mlp_w + (size_t)lane * DF);
#pragma unroll
  for (int k = 0; k < DF / 4; ++k) {
    float4 t = wp[k];
    wr[4 * k] = t.x; wr[4 * k + 1] = t.y; wr[4 * k + 2] = t.z; wr[4 * k + 3] = t.w;
  }
  float bias = mlp_b[lane];
  int nw = (gridDim.x * blockDim.x) >> 6;
  int w0 = (blockIdx.x * blockDim.x + threadIdx.x) >> 6;
  for (int r = w0; r < NTOT; r += nw) {
    float v;
    if (r < NUSER) {          // wave-uniform branch (r is wave-uniform)
      v = pref[(size_t)r * D + lane];
    } else {
      const float4* fr = (const float4*)(feat + (size_t)(r - NUSER) * DF);
      float acc = bias;
#pragma unroll
      for (int k = 0; k < DF / 4; ++k) {
        float4 a = fr[k];  // wave-uniform address -> L1 broadcast
        acc += a.x * wr[4 * k] + a.y * wr[4 * k + 1] + a.z * wr[4 * k + 2] + a.w * wr[4 * k + 3];
      }
      v = acc;
    }
    float ss = v * v;
#pragma unroll
    for (int o = 32; o; o >>= 1) ss += __shfl_xor(ss, o);
    float inv = 1.0f / fmaxf(sqrtf(ss), 1e-12f);
    x[(size_t)r * D + lane] = v * inv;
  }
}

// ---------------------------------------------------------------------------
// CSR build: histogram of dst, 3-phase exclusive scan, cursor scatter.
__global__ void k_hist(const int* __restrict__ dst, int* __restrict__ deg) {
  int e = blockIdx.x * blockDim.x + threadIdx.x;
  if (e < NE) atomicAdd(&deg[dst[e]], 1);
}

__global__ void k_scan1(const int* __restrict__ deg, int* __restrict__ bsum) {
  __shared__ int s[SCANB];
  int i = blockIdx.x * SCANB + threadIdx.x;
  s[threadIdx.x] = (i < NTOT) ? deg[i] : 0;
  __syncthreads();
  for (int o = SCANB / 2; o; o >>= 1) {
    if (threadIdx.x < o) s[threadIdx.x] += s[threadIdx.x + o];
    __syncthreads();
  }
  if (threadIdx.x == 0) bsum[blockIdx.x] = s[0];
}

__global__ void k_scan2(int* __restrict__ bsum) {  // single block of 512
  __shared__ int s[512];
  int t = threadIdx.x;
  int v = (t < NBLK) ? bsum[t] : 0;
  s[t] = v;
  __syncthreads();
  for (int o = 1; o < 512; o <<= 1) {
    int a = (t >= o) ? s[t - o] : 0;
    __syncthreads();
    s[t] += a;
    __syncthreads();
  }
  if (t < NBLK) bsum[t] = s[t] - v;  // exclusive
}

__global__ void k_scan3(const int* __restrict__ deg, const int* __restrict__ bsum,
                        int* __restrict__ rowptr, int* __restrict__ cursor) {
  __shared__ int s[SCANB];
  int t = threadIdx.x;
  int i = blockIdx.x * SCANB + t;
  int v = (i < NTOT) ? deg[i] : 0;
  s[t] = v;
  __syncthreads();
  for (int o = 1; o < SCANB; o <<= 1) {
    int a = (t >= o) ? s[t - o] : 0;
    __syncthreads();
    s[t] += a;
    __syncthreads();
  }
  if (i < NTOT) {
    int ex = s[t] - v + bsum[blockIdx.x];
    rowptr[i] = ex;
    cursor[i] = ex;
  }
  if (i == 0) rowptr[NTOT] = NE;
}

__global__ void k_scatter(const int* __restrict__ src, const int* __restrict__ dst,
                          int* __restrict__ cursor, int* __restrict__ csr) {
  int e = blockIdx.x * blockDim.x + threadIdx.x;
  if (e < NE) {
    int p = atomicAdd(&cursor[dst[e]], 1);
    csr[p] = src[e];
  }
}

// ---------------------------------------------------------------------------
// agg[n] = sum over incoming edges of x[src]. One wave per node, no atomics.
// 4-way edge unroll -> 4 independent gathers in flight per wave; row bounds
// forced to SGPRs so csr[] reads go down the scalar path.
__global__ __launch_bounds__(256) void k_agg(
    const float* __restrict__ x, const int* __restrict__ rowptr,
    const int* __restrict__ csr, float* __restrict__ agg) {
  int wid  = (blockIdx.x * blockDim.x + threadIdx.x) >> 6;
  int lane = threadIdx.x & 63;
  if (wid >= NTOT) return;
  int e0 = __builtin_amdgcn_readfirstlane(rowptr[wid]);
  int e1 = __builtin_amdgcn_readfirstlane(rowptr[wid + 1]);
  float a0 = 0.f, a1 = 0.f, a2 = 0.f, a3 = 0.f;
  int e = e0;
  for (; e + 4 <= e1; e += 4) {
    int s0 = __builtin_amdgcn_readfirstlane(csr[e]);
    int s1 = __builtin_amdgcn_readfirstlane(csr[e + 1]);
    int s2 = __builtin_amdgcn_readfirstlane(csr[e + 2]);
    int s3 = __builtin_amdgcn_readfirstlane(csr[e + 3]);
    a0 += x[(size_t)s0 * D + lane];
    a1 += x[(size_t)s1 * D + lane];
    a2 += x[(size_t)s2 * D + lane];
    a3 += x[(size_t)s3 * D + lane];
  }
  for (; e < e1; ++e) {
    int s = __builtin_amdgcn_readfirstlane(csr[e]);
    a0 += x[(size_t)s * D + lane];
  }
  agg[(size_t)wid * D + lane] = (a0 + a1) + (a2 + a3);
}

// ---------------------------------------------------------------------------
// hOut[r]  = leaky(aggIn[r] @ conv_w)            (conv_w is [k][j], [in,out])
// xhOut[r] = leaky(xIn[r] @ lin_w.T + lin_b)     (lin_w is [j][k], [out,in])
// May run IN-PLACE (hOut==aggIn, xhOut==xIn): each row is owned by exactly
// one wave; stores depend on that row's loads through registers, and
// cross-row pipelining touches disjoint addresses.
__global__ __launch_bounds__(256) void k_hx(
    const float* __restrict__ aggIn, const float* __restrict__ xIn,
    const float* __restrict__ convw, const float* __restrict__ linw,
    const float* __restrict__ linb,
    float* __restrict__ hOut, float* __restrict__ xhOut) {
  int lane = threadIdx.x & 63;
  float wc[D], wl[D];
#pragma unroll
  for (int k = 0; k < D; ++k) wc[k] = convw[k * D + lane];  // column `lane`
  const float4* lr = (const float4*)(linw + (size_t)lane * D);
#pragma unroll
  for (int k = 0; k < D / 4; ++k) {
    float4 t = lr[k];
    wl[4 * k] = t.x; wl[4 * k + 1] = t.y; wl[4 * k + 2] = t.z; wl[4 * k + 3] = t.w;
  }
  float bias = linb[lane];
  int nw   = (gridDim.x * blockDim.x) >> 6;
  int wid0 = (blockIdx.x * blockDim.x + threadIdx.x) >> 6;
  for (int r = wid0; r < NTOT; r += nw) {
    const float4* ar = (const float4*)(aggIn + (size_t)r * D);
    const float4* xr = (const float4*)(xIn + (size_t)r * D);
    float h = 0.f, xh = bias;
#pragma unroll
    for (int k = 0; k < D / 4; ++k) {
      float4 a = ar[k];  // wave-uniform -> L1 broadcast
      float4 b = xr[k];
      h  += a.x * wc[4 * k] + a.y * wc[4 * k + 1] + a.z * wc[4 * k + 2] + a.w * wc[4 * k + 3];
      xh += b.x * wl[4 * k] + b.y * wl[4 * k + 1] + b.z * wl[4 * k + 2] + b.w * wl[4 * k + 3];
    }
    hOut[(size_t)r * D + lane]  = leaky(h);
    xhOut[(size_t)r * D + lane] = leaky(xh);
  }
}

// out[r] = (leaky?) (h[r] @ gw[:, :64].T + xh[r] @ gw[:, 64:].T + g_b)
// gw is [j][k] with k in [0,128). out may alias h.
__global__ __launch_bounds__(256) void k_g(
    const float* __restrict__ h, const float* __restrict__ xh,
    const float* __restrict__ gw, const float* __restrict__ gb,
    float* __restrict__ out, int do_leaky) {
  int lane = threadIdx.x & 63;
  float whr[D], wxr[D];
  const float4* g0 = (const float4*)(gw + (size_t)lane * 2 * D);
  const float4* g1 = (const float4*)(gw + (size_t)lane * 2 * D + D);
#pragma unroll
  for (int k = 0; k < D / 4; ++k) {
    float4 t0 = g0[k];
    whr[4 * k] = t0.x; whr[4 * k + 1] = t0.y; whr[4 * k + 2] = t0.z; whr[4 * k + 3] = t0.w;
    float4 t1 = g1[k];
    wxr[4 * k] = t1.x; wxr[4 * k + 1] = t1.y; wxr[4 * k + 2] = t1.z; wxr[4 * k + 3] = t1.w;
  }
  float bias = gb[lane];
  int nw   = (gridDim.x * blockDim.x) >> 6;
  int wid0 = (blockIdx.x * blockDim.x + threadIdx.x) >> 6;
  for (int r = wid0; r < NTOT; r += nw) {
    const float4* hr = (const float4*)(h + (size_t)r * D);
    const float4* xr = (const float4*)(xh + (size_t)r * D);
    float acc = bias;
#pragma unroll
    for (int k = 0; k < D / 4; ++k) {
      float4 a = hr[k];
      float4 b = xr[k];
      acc += a.x * whr[4 * k] + a.y * whr[4 * k + 1] + a.z * whr[4 * k + 2] + a.w * whr[4 * k + 3];
      acc += b.x * wxr[4 * k] + b.y * wxr[4 * k + 1] + b.z * wxr[4 * k + 2] + b.w * wxr[4 * k + 3];
    }
    if (do_leaky) acc = leaky(acc);
    out[(size_t)r * D + lane] = acc;
  }
}

// ---------------------------------------------------------------------------
extern "C" void kernel_launch(void* const* d_in, const int* in_sizes, int n_in,
                              void* d_out, int out_size, void* d_ws, size_t ws_size,
                              hipStream_t stream) {
  const float* features = (const float*)d_in[0];
  const int*   ei       = (const int*)d_in[1];
  const float* pref     = (const float*)d_in[2];
  const float* mlp_w    = (const float*)d_in[3];
  const float* mlp_b    = (const float*)d_in[4];
  const float* conv_w[5]; const float* lin_w[5]; const float* lin_b[5];
  const float* g_w[5];    const float* g_b[5];
  if (n_in >= 30) {
    for (int i = 0; i < 5; ++i) {
      conv_w[i] = (const float*)d_in[5 + i];
      lin_w[i]  = (const float*)d_in[10 + i];
      lin_b[i]  = (const float*)d_in[15 + i];
      g_w[i]    = (const float*)d_in[20 + i];
      g_b[i]    = (const float*)d_in[25 + i];
    }
  } else {
    const float* cw = (const float*)d_in[5];
    const float* lw = (const float*)d_in[6];
    const float* lb = (const float*)d_in[7];
    const float* gw = (const float*)d_in[8];
    const float* gb = (const float*)d_in[9];
    for (int i = 0; i < 5; ++i) {
      conv_w[i] = cw + (size_t)i * D * D;
      lin_w[i]  = lw + (size_t)i * D * D;
      lin_b[i]  = lb + (size_t)i * D;
      g_w[i]    = gw + (size_t)i * D * 2 * D;
      g_b[i]    = gb + (size_t)i * D;
    }
  }
  const int* e_src = ei;
  const int* e_dst = ei + NE;

  char* p = (char*)d_ws;
  float* xa     = (float*)p; p += (size_t)NTOT * D * 4;        // 25.6 MB
  float* xb     = (float*)p; p += (size_t)NTOT * D * 4;        // 25.6 MB
  float* agg    = (float*)p; p += (size_t)NTOT * D * 4;        // 25.6 MB
  int*   csr    = (int*)p;   p += (size_t)NE * 4;              // 8 MB
  int*   deg    = (int*)p;   p += (size_t)NTOT * 4;
  int*   rowptr = (int*)p;   p += (size_t)(NTOT + 4) * 4;
  int*   cursor = (int*)p;   p += (size_t)NTOT * 4;
  int*   bsum   = (int*)p;   p += 1024 * 4;
  // total ~86.4 MB

  float* mu     = (float*)d_out;
  float* logvar = (float*)d_out + (size_t)NTOT * D;

  const int WPB = 4;  // waves per block (block = 256)
  int grid_rows  = (NTOT + WPB - 1) / WPB;        // 25000
  int grid_edges = (NE + 255) / 256;              // 7813
  int grid_dense = 1792;                          // grid-stride dense kernels

  // x = normalize(concat(preference, features @ mlp_w.T + mlp_b))
  k_init<<<grid_dense, 256, 0, stream>>>(features, pref, mlp_w, mlp_b, xa);

  // CSR by dst (rebuilt every call; deterministic work)
  k_zero<<<(NTOT + 255) / 256, 256, 0, stream>>>(deg, NTOT);
  k_hist<<<grid_edges, 256, 0, stream>>>(e_dst, deg);
  k_scan1<<<NBLK, SCANB, 0, stream>>>(deg, bsum);
  k_scan2<<<1, 512, 0, stream>>>(bsum);
  k_scan3<<<NBLK, SCANB, 0, stream>>>(deg, bsum, rowptr, cursor);
  k_scatter<<<grid_edges, 256, 0, stream>>>(e_src, e_dst, cursor, csr);

  for (int i = 0; i < 3; ++i) {
    k_agg<<<grid_rows, 256, 0, stream>>>(xa, rowptr, csr, agg);
    // in-place: h over agg, xh over xa
    k_hx<<<grid_dense, 256, 0, stream>>>(agg, xa, conv_w[i], lin_w[i], lin_b[i], agg, xa);
    k_g<<<grid_dense, 256, 0, stream>>>(agg, xa, g_w[i], g_b[i], xb, 1);
    float* t = xa; xa = xb; xb = t;
  }

  // Heads share one aggregation of the final x.
  k_agg<<<grid_rows, 256, 0, stream>>>(xa, rowptr, csr, agg);
  k_hx<<<grid_dense, 256, 0, stream>>>(agg, xa, conv_w[3], lin_w[3], lin_b[3], mu, xb);
  k_g<<<grid_dense, 256, 0, stream>>>(mu, xb, g_w[3], g_b[3], mu, 0);
  k_hx<<<grid_dense, 256, 0, stream>>>(agg, xa, conv_w[4], lin_w[4], lin_b[4], logvar, xb);
  k_g<<<grid_dense, 256, 0, stream>>>(logvar, xb, g_w[4], g_b[4], logvar, 0);
}

// Round 4
// 1440.991 us; speedup vs baseline: 2.2664x; 1.8796x over previous
//
#include <hip/hip_runtime.h>

#define DEVINL __device__ __forceinline__

constexpr int NUSER = 50000;
constexpr int NTOT  = 100000;   // NUM_USER + NUM_ITEM
constexpr int DF    = 128;
constexpr int D     = 64;
constexpr int NE    = 2000000;
constexpr int SCANB = 256;
constexpr int NBLK  = (NTOT + SCANB - 1) / SCANB;  // 391
constexpr int TR    = 32;       // dense-kernel tile rows (100000 % 32 == 0 ... 3125 tiles)

DEVINL float leaky(float v) { return v > 0.f ? v : 0.01f * v; }

// ---------------------------------------------------------------------------
__global__ __launch_bounds__(256) void k_zero(int* __restrict__ p, int n) {
  int i = blockIdx.x * blockDim.x + threadIdx.x;
  if (i < n) p[i] = 0;
}

// ---------------------------------------------------------------------------
// x[0:NUSER] = preference; x[NUSER:] = features @ mlp_w.T + mlp_b; then
// row-normalize. Grid-stride, one wave per row, mlp_w row held in VGPRs.
__global__ __launch_bounds__(256) void k_init(
    const float* __restrict__ feat, const float* __restrict__ pref,
    const float* __restrict__ mlp_w, const float* __restrict__ mlp_b,
    float* __restrict__ x) {
  int lane = threadIdx.x & 63;
  float wr[DF];
  const float4* wp = (const float4*)(mlp_w + (size_t)lane * DF);
#pragma unroll
  for (int k = 0; k < DF / 4; ++k) {
    float4 t = wp[k];
    wr[4 * k] = t.x; wr[4 * k + 1] = t.y; wr[4 * k + 2] = t.z; wr[4 * k + 3] = t.w;
  }
  float bias = mlp_b[lane];
  int nw = (gridDim.x * blockDim.x) >> 6;
  int w0 = (blockIdx.x * blockDim.x + threadIdx.x) >> 6;
  for (int r = w0; r < NTOT; r += nw) {
    float v;
    if (r < NUSER) {          // wave-uniform branch
      v = pref[(size_t)r * D + lane];
    } else {
      const float4* fr = (const float4*)(feat + (size_t)(r - NUSER) * DF);
      float acc = bias;
#pragma unroll
      for (int k = 0; k < DF / 4; ++k) {
        float4 a = fr[k];
        acc += a.x * wr[4 * k] + a.y * wr[4 * k + 1] + a.z * wr[4 * k + 2] + a.w * wr[4 * k + 3];
      }
      v = acc;
    }
    float ss = v * v;
#pragma unroll
    for (int o = 32; o; o >>= 1) ss += __shfl_xor(ss, o);
    float inv = 1.0f / fmaxf(sqrtf(ss), 1e-12f);
    x[(size_t)r * D + lane] = v * inv;
  }
}

// ---------------------------------------------------------------------------
// CSR build: histogram of dst, 3-phase exclusive scan, cursor scatter.
__global__ void k_hist(const int* __restrict__ dst, int* __restrict__ deg) {
  int e = blockIdx.x * blockDim.x + threadIdx.x;
  if (e < NE) atomicAdd(&deg[dst[e]], 1);
}

__global__ void k_scan1(const int* __restrict__ deg, int* __restrict__ bsum) {
  __shared__ int s[SCANB];
  int i = blockIdx.x * SCANB + threadIdx.x;
  s[threadIdx.x] = (i < NTOT) ? deg[i] : 0;
  __syncthreads();
  for (int o = SCANB / 2; o; o >>= 1) {
    if (threadIdx.x < o) s[threadIdx.x] += s[threadIdx.x + o];
    __syncthreads();
  }
  if (threadIdx.x == 0) bsum[blockIdx.x] = s[0];
}

__global__ void k_scan2(int* __restrict__ bsum) {  // single block of 512
  __shared__ int s[512];
  int t = threadIdx.x;
  int v = (t < NBLK) ? bsum[t] : 0;
  s[t] = v;
  __syncthreads();
  for (int o = 1; o < 512; o <<= 1) {
    int a = (t >= o) ? s[t - o] : 0;
    __syncthreads();
    s[t] += a;
    __syncthreads();
  }
  if (t < NBLK) bsum[t] = s[t] - v;  // exclusive
}

__global__ void k_scan3(const int* __restrict__ deg, const int* __restrict__ bsum,
                        int* __restrict__ rowptr, int* __restrict__ cursor) {
  __shared__ int s[SCANB];
  int t = threadIdx.x;
  int i = blockIdx.x * SCANB + t;
  int v = (i < NTOT) ? deg[i] : 0;
  s[t] = v;
  __syncthreads();
  for (int o = 1; o < SCANB; o <<= 1) {
    int a = (t >= o) ? s[t - o] : 0;
    __syncthreads();
    s[t] += a;
    __syncthreads();
  }
  if (i < NTOT) {
    int ex = s[t] - v + bsum[blockIdx.x];
    rowptr[i] = ex;
    cursor[i] = ex;
  }
  if (i == 0) rowptr[NTOT] = NE;
}

__global__ void k_scatter(const int* __restrict__ src, const int* __restrict__ dst,
                          int* __restrict__ cursor, int* __restrict__ csr) {
  int e = blockIdx.x * blockDim.x + threadIdx.x;
  if (e < NE) {
    int p = atomicAdd(&cursor[dst[e]], 1);
    csr[p] = src[e];
  }
}

// ---------------------------------------------------------------------------
// agg[n] = sum over incoming edges of x[src]. One wave per node, no atomics.
__global__ __launch_bounds__(256) void k_agg(
    const float* __restrict__ x, const int* __restrict__ rowptr,
    const int* __restrict__ csr, float* __restrict__ agg) {
  int wid  = (blockIdx.x * blockDim.x + threadIdx.x) >> 6;
  int lane = threadIdx.x & 63;
  if (wid >= NTOT) return;
  int e0 = __builtin_amdgcn_readfirstlane(rowptr[wid]);
  int e1 = __builtin_amdgcn_readfirstlane(rowptr[wid + 1]);
  float a0 = 0.f, a1 = 0.f, a2 = 0.f, a3 = 0.f;
  int e = e0;
  for (; e + 4 <= e1; e += 4) {
    int s0 = __builtin_amdgcn_readfirstlane(csr[e]);
    int s1 = __builtin_amdgcn_readfirstlane(csr[e + 1]);
    int s2 = __builtin_amdgcn_readfirstlane(csr[e + 2]);
    int s3 = __builtin_amdgcn_readfirstlane(csr[e + 3]);
    a0 += x[(size_t)s0 * D + lane];
    a1 += x[(size_t)s1 * D + lane];
    a2 += x[(size_t)s2 * D + lane];
    a3 += x[(size_t)s3 * D + lane];
  }
  for (; e < e1; ++e) {
    int s = __builtin_amdgcn_readfirstlane(csr[e]);
    a0 += x[(size_t)s * D + lane];
  }
  agg[(size_t)wid * D + lane] = (a0 + a1) + (a2 + a3);
}

// ---------------------------------------------------------------------------
// LDS-staged dense kernels. A block stages a TR-row tile of the inputs with
// coalesced float4 loads, then each wave computes TR/4 rows from LDS
// broadcasts against per-lane weight columns in VGPRs. Grid-stride over
// tiles with register double-buffering so next-tile loads overlap compute.
// In-place safe: within a block, tile-t loads precede tile-t stores, and
// tiles are disjoint across blocks.

// hOut[r] = leaky(aggIn[r] @ conv_w); xhOut[r] = leaky(xIn[r] @ lin_w.T + b)
__global__ __launch_bounds__(256) void k_hx(
    const float* __restrict__ aggIn, const float* __restrict__ xIn,
    const float* __restrict__ convw, const float* __restrict__ linw,
    const float* __restrict__ linb,
    float* __restrict__ hOut, float* __restrict__ xhOut) {
  __shared__ float sA[2][TR * D];
  __shared__ float sX[2][TR * D];
  int tid  = threadIdx.x;
  int lane = tid & 63;
  int wv   = tid >> 6;
  float wc[D], wl[D];
#pragma unroll
  for (int k = 0; k < D; ++k) wc[k] = convw[k * D + lane];  // column `lane`
  const float4* lr = (const float4*)(linw + (size_t)lane * D);
#pragma unroll
  for (int k = 0; k < D / 4; ++k) {
    float4 t = lr[k];
    wl[4 * k] = t.x; wl[4 * k + 1] = t.y; wl[4 * k + 2] = t.z; wl[4 * k + 3] = t.w;
  }
  float bias = linb[lane];
  const int ntile = NTOT / TR;
  float4 pA0, pA1, pX0, pX1;
  int t = blockIdx.x;
  {
    const float4* a = (const float4*)(aggIn + (size_t)t * TR * D);
    const float4* x = (const float4*)(xIn + (size_t)t * TR * D);
    pA0 = a[tid]; pA1 = a[tid + 256]; pX0 = x[tid]; pX1 = x[tid + 256];
  }
  {
    float4* da = (float4*)sA[0]; da[tid] = pA0; da[tid + 256] = pA1;
    float4* dx = (float4*)sX[0]; dx[tid] = pX0; dx[tid + 256] = pX1;
  }
  __syncthreads();
  int buf = 0;
  for (; t < ntile; t += gridDim.x) {
    int tn = t + gridDim.x;
    if (tn < ntile) {  // prefetch next tile into regs (overlaps compute)
      const float4* a = (const float4*)(aggIn + (size_t)tn * TR * D);
      const float4* x = (const float4*)(xIn + (size_t)tn * TR * D);
      pA0 = a[tid]; pA1 = a[tid + 256]; pX0 = x[tid]; pX1 = x[tid + 256];
    }
#pragma unroll
    for (int rr = 0; rr < TR / 4; ++rr) {
      int r = wv * (TR / 4) + rr;
      const float4* ar = (const float4*)&sA[buf][r * D];
      const float4* xr = (const float4*)&sX[buf][r * D];
      float h = 0.f, xh = bias;
#pragma unroll
      for (int k = 0; k < D / 4; ++k) {
        float4 a = ar[k];  // uniform LDS read -> broadcast
        float4 b = xr[k];
        h  += a.x * wc[4 * k] + a.y * wc[4 * k + 1] + a.z * wc[4 * k + 2] + a.w * wc[4 * k + 3];
        xh += b.x * wl[4 * k] + b.y * wl[4 * k + 1] + b.z * wl[4 * k + 2] + b.w * wl[4 * k + 3];
      }
      size_t gr = (size_t)t * TR + r;
      hOut[gr * D + lane]  = leaky(h);
      xhOut[gr * D + lane] = leaky(xh);
    }
    __syncthreads();   // all waves done reading buf (and prev writes to buf^1 consumed)
    if (tn < ntile) {
      float4* da = (float4*)sA[buf ^ 1]; da[tid] = pA0; da[tid + 256] = pA1;
      float4* dx = (float4*)sX[buf ^ 1]; dx[tid] = pX0; dx[tid + 256] = pX1;
    }
    __syncthreads();
    buf ^= 1;
  }
}

// out[r] = (leaky?)(h[r] @ gw[:, :64].T + xh[r] @ gw[:, 64:].T + g_b)
__global__ __launch_bounds__(256) void k_g(
    const float* __restrict__ h, const float* __restrict__ xh,
    const float* __restrict__ gw, const float* __restrict__ gb,
    float* __restrict__ out, int do_leaky) {
  __shared__ float sH[2][TR * D];
  __shared__ float sX[2][TR * D];
  int tid  = threadIdx.x;
  int lane = tid & 63;
  int wv   = tid >> 6;
  float whr[D], wxr[D];
  const float4* g0 = (const float4*)(gw + (size_t)lane * 2 * D);
  const float4* g1 = (const float4*)(gw + (size_t)lane * 2 * D + D);
#pragma unroll
  for (int k = 0; k < D / 4; ++k) {
    float4 t0 = g0[k];
    whr[4 * k] = t0.x; whr[4 * k + 1] = t0.y; whr[4 * k + 2] = t0.z; whr[4 * k + 3] = t0.w;
    float4 t1 = g1[k];
    wxr[4 * k] = t1.x; wxr[4 * k + 1] = t1.y; wxr[4 * k + 2] = t1.z; wxr[4 * k + 3] = t1.w;
  }
  float bias = gb[lane];
  const int ntile = NTOT / TR;
  float4 pH0, pH1, pX0, pX1;
  int t = blockIdx.x;
  {
    const float4* a = (const float4*)(h + (size_t)t * TR * D);
    const float4* x = (const float4*)(xh + (size_t)t * TR * D);
    pH0 = a[tid]; pH1 = a[tid + 256]; pX0 = x[tid]; pX1 = x[tid + 256];
  }
  {
    float4* da = (float4*)sH[0]; da[tid] = pH0; da[tid + 256] = pH1;
    float4* dx = (float4*)sX[0]; dx[tid] = pX0; dx[tid + 256] = pX1;
  }
  __syncthreads();
  int buf = 0;
  for (; t < ntile; t += gridDim.x) {
    int tn = t + gridDim.x;
    if (tn < ntile) {
      const float4* a = (const float4*)(h + (size_t)tn * TR * D);
      const float4* x = (const float4*)(xh + (size_t)tn * TR * D);
      pH0 = a[tid]; pH1 = a[tid + 256]; pX0 = x[tid]; pX1 = x[tid + 256];
    }
#pragma unroll
    for (int rr = 0; rr < TR / 4; ++rr) {
      int r = wv * (TR / 4) + rr;
      const float4* hr = (const float4*)&sH[buf][r * D];
      const float4* xr = (const float4*)&sX[buf][r * D];
      float acc = bias;
#pragma unroll
      for (int k = 0; k < D / 4; ++k) {
        float4 a = hr[k];
        float4 b = xr[k];
        acc += a.x * whr[4 * k] + a.y * whr[4 * k + 1] + a.z * whr[4 * k + 2] + a.w * whr[4 * k + 3];
        acc += b.x * wxr[4 * k] + b.y * wxr[4 * k + 1] + b.z * wxr[4 * k + 2] + b.w * wxr[4 * k + 3];
      }
      if (do_leaky) acc = leaky(acc);
      out[((size_t)t * TR + r) * D + lane] = acc;
    }
    __syncthreads();
    if (tn < ntile) {
      float4* da = (float4*)sH[buf ^ 1]; da[tid] = pH0; da[tid + 256] = pH1;
      float4* dx = (float4*)sX[buf ^ 1]; dx[tid] = pX0; dx[tid + 256] = pX1;
    }
    __syncthreads();
    buf ^= 1;
  }
}

// ---------------------------------------------------------------------------
extern "C" void kernel_launch(void* const* d_in, const int* in_sizes, int n_in,
                              void* d_out, int out_size, void* d_ws, size_t ws_size,
                              hipStream_t stream) {
  const float* features = (const float*)d_in[0];
  const int*   ei       = (const int*)d_in[1];
  const float* pref     = (const float*)d_in[2];
  const float* mlp_w    = (const float*)d_in[3];
  const float* mlp_b    = (const float*)d_in[4];
  const float* conv_w[5]; const float* lin_w[5]; const float* lin_b[5];
  const float* g_w[5];    const float* g_b[5];
  if (n_in >= 30) {
    for (int i = 0; i < 5; ++i) {
      conv_w[i] = (const float*)d_in[5 + i];
      lin_w[i]  = (const float*)d_in[10 + i];
      lin_b[i]  = (const float*)d_in[15 + i];
      g_w[i]    = (const float*)d_in[20 + i];
      g_b[i]    = (const float*)d_in[25 + i];
    }
  } else {
    const float* cw = (const float*)d_in[5];
    const float* lw = (const float*)d_in[6];
    const float* lb = (const float*)d_in[7];
    const float* gw = (const float*)d_in[8];
    const float* gb = (const float*)d_in[9];
    for (int i = 0; i < 5; ++i) {
      conv_w[i] = cw + (size_t)i * D * D;
      lin_w[i]  = lw + (size_t)i * D * D;
      lin_b[i]  = lb + (size_t)i * D;
      g_w[i]    = gw + (size_t)i * D * 2 * D;
      g_b[i]    = gb + (size_t)i * D;
    }
  }
  const int* e_src = ei;
  const int* e_dst = ei + NE;

  char* p = (char*)d_ws;
  float* xa     = (float*)p; p += (size_t)NTOT * D * 4;        // 25.6 MB
  float* xb     = (float*)p; p += (size_t)NTOT * D * 4;        // 25.6 MB
  float* agg    = (float*)p; p += (size_t)NTOT * D * 4;        // 25.6 MB
  int*   csr    = (int*)p;   p += (size_t)NE * 4;              // 8 MB
  int*   deg    = (int*)p;   p += (size_t)NTOT * 4;
  int*   rowptr = (int*)p;   p += (size_t)(NTOT + 4) * 4;
  int*   cursor = (int*)p;   p += (size_t)NTOT * 4;
  int*   bsum   = (int*)p;   p += 1024 * 4;
  // total ~86.4 MB

  float* mu     = (float*)d_out;
  float* logvar = (float*)d_out + (size_t)NTOT * D;

  const int WPB = 4;
  int grid_rows  = (NTOT + WPB - 1) / WPB;        // 25000
  int grid_edges = (NE + 255) / 256;              // 7813
  int grid_dense = 1024;                          // tile grid-stride (3125 tiles)

  k_init<<<1792, 256, 0, stream>>>(features, pref, mlp_w, mlp_b, xa);

  // CSR by dst (rebuilt every call; deterministic work)
  k_zero<<<(NTOT + 255) / 256, 256, 0, stream>>>(deg, NTOT);
  k_hist<<<grid_edges, 256, 0, stream>>>(e_dst, deg);
  k_scan1<<<NBLK, SCANB, 0, stream>>>(deg, bsum);
  k_scan2<<<1, 512, 0, stream>>>(bsum);
  k_scan3<<<NBLK, SCANB, 0, stream>>>(deg, bsum, rowptr, cursor);
  k_scatter<<<grid_edges, 256, 0, stream>>>(e_src, e_dst, cursor, csr);

  for (int i = 0; i < 3; ++i) {
    k_agg<<<grid_rows, 256, 0, stream>>>(xa, rowptr, csr, agg);
    k_hx<<<grid_dense, 256, 0, stream>>>(agg, xa, conv_w[i], lin_w[i], lin_b[i], agg, xa);
    k_g<<<grid_dense, 256, 0, stream>>>(agg, xa, g_w[i], g_b[i], xb, 1);
    float* t = xa; xa = xb; xb = t;
  }

  // Heads share one aggregation of the final x.
  k_agg<<<grid_rows, 256, 0, stream>>>(xa, rowptr, csr, agg);
  k_hx<<<grid_dense, 256, 0, stream>>>(agg, xa, conv_w[3], lin_w[3], lin_b[3], mu, xb);
  k_g<<<grid_dense, 256, 0, stream>>>(mu, xb, g_w[3], g_b[3], mu, 0);
  k_hx<<<grid_dense, 256, 0, stream>>>(agg, xa, conv_w[4], lin_w[4], lin_b[4], logvar, xb);
  k_g<<<grid_dense, 256, 0, stream>>>(logvar, xb, g_w[4], g_b[4], logvar, 0);
}

// Round 5
// 1176.671 us; speedup vs baseline: 2.7755x; 1.2246x over previous
//
#include <hip/hip_runtime.h>
#include <hip/hip_fp16.h>

#define DEVINL __device__ __forceinline__

constexpr int NUSER = 50000;
constexpr int NTOT  = 100000;   // NUM_USER + NUM_ITEM
constexpr int DF    = 128;
constexpr int D     = 64;
constexpr int NE    = 2000000;
constexpr int SCANB = 256;
constexpr int NBLK  = (NTOT + SCANB - 1) / SCANB;  // 391
constexpr int TR    = 32;       // dense-kernel tile rows (3125 tiles)

DEVINL float leaky(float v) { return v > 0.f ? v : 0.01f * v; }

DEVINL float2 h2f2(unsigned u) {
  __half2 h = *reinterpret_cast<__half2*>(&u);
  return __half22float2(h);
}

// ---------------------------------------------------------------------------
__global__ __launch_bounds__(256) void k_zero(int* __restrict__ p, int n) {
  int i = blockIdx.x * blockDim.x + threadIdx.x;
  if (i < n) p[i] = 0;
}

// ---------------------------------------------------------------------------
// x16[0:NUSER] = preference; rest = features @ mlp_w.T + mlp_b; row-normalize.
// f32 compute, fp16 store. One wave per row, mlp_w row in VGPRs.
__global__ __launch_bounds__(256) void k_init(
    const float* __restrict__ feat, const float* __restrict__ pref,
    const float* __restrict__ mlp_w, const float* __restrict__ mlp_b,
    __half* __restrict__ x16) {
  int lane = threadIdx.x & 63;
  float wr[DF];
  const float4* wp = (const float4*)(mlp_w + (size_t)lane * DF);
#pragma unroll
  for (int k = 0; k < DF / 4; ++k) {
    float4 t = wp[k];
    wr[4 * k] = t.x; wr[4 * k + 1] = t.y; wr[4 * k + 2] = t.z; wr[4 * k + 3] = t.w;
  }
  float bias = mlp_b[lane];
  int nw = (gridDim.x * blockDim.x) >> 6;
  int w0 = (blockIdx.x * blockDim.x + threadIdx.x) >> 6;
  for (int r = w0; r < NTOT; r += nw) {
    float v;
    if (r < NUSER) {          // wave-uniform branch
      v = pref[(size_t)r * D + lane];
    } else {
      const float4* fr = (const float4*)(feat + (size_t)(r - NUSER) * DF);
      float acc = bias;
#pragma unroll
      for (int k = 0; k < DF / 4; ++k) {
        float4 a = fr[k];
        acc += a.x * wr[4 * k] + a.y * wr[4 * k + 1] + a.z * wr[4 * k + 2] + a.w * wr[4 * k + 3];
      }
      v = acc;
    }
    float ss = v * v;
#pragma unroll
    for (int o = 32; o; o >>= 1) ss += __shfl_xor(ss, o);
    float inv = 1.0f / fmaxf(sqrtf(ss), 1e-12f);
    x16[(size_t)r * D + lane] = __float2half(v * inv);
  }
}

// ---------------------------------------------------------------------------
// CSR build: histogram of dst, 3-phase exclusive scan, cursor scatter.
__global__ void k_hist(const int* __restrict__ dst, int* __restrict__ deg) {
  int e = blockIdx.x * blockDim.x + threadIdx.x;
  if (e < NE) atomicAdd(&deg[dst[e]], 1);
}

__global__ void k_scan1(const int* __restrict__ deg, int* __restrict__ bsum) {
  __shared__ int s[SCANB];
  int i = blockIdx.x * SCANB + threadIdx.x;
  s[threadIdx.x] = (i < NTOT) ? deg[i] : 0;
  __syncthreads();
  for (int o = SCANB / 2; o; o >>= 1) {
    if (threadIdx.x < o) s[threadIdx.x] += s[threadIdx.x + o];
    __syncthreads();
  }
  if (threadIdx.x == 0) bsum[blockIdx.x] = s[0];
}

__global__ void k_scan2(int* __restrict__ bsum) {  // single block of 512
  __shared__ int s[512];
  int t = threadIdx.x;
  int v = (t < NBLK) ? bsum[t] : 0;
  s[t] = v;
  __syncthreads();
  for (int o = 1; o < 512; o <<= 1) {
    int a = (t >= o) ? s[t - o] : 0;
    __syncthreads();
    s[t] += a;
    __syncthreads();
  }
  if (t < NBLK) bsum[t] = s[t] - v;  // exclusive
}

__global__ void k_scan3(const int* __restrict__ deg, const int* __restrict__ bsum,
                        int* __restrict__ rowptr, int* __restrict__ cursor) {
  __shared__ int s[SCANB];
  int t = threadIdx.x;
  int i = blockIdx.x * SCANB + t;
  int v = (i < NTOT) ? deg[i] : 0;
  s[t] = v;
  __syncthreads();
  for (int o = 1; o < SCANB; o <<= 1) {
    int a = (t >= o) ? s[t - o] : 0;
    __syncthreads();
    s[t] += a;
    __syncthreads();
  }
  if (i < NTOT) {
    int ex = s[t] - v + bsum[blockIdx.x];
    rowptr[i] = ex;
    cursor[i] = ex;
  }
  if (i == 0) rowptr[NTOT] = NE;
}

__global__ void k_scatter(const int* __restrict__ src, const int* __restrict__ dst,
                          int* __restrict__ cursor, int* __restrict__ csr) {
  int e = blockIdx.x * blockDim.x + threadIdx.x;
  if (e < NE) {
    int p = atomicAdd(&cursor[dst[e]], 1);
    __builtin_nontemporal_store(src[e], &csr[p]);
  }
}

// ---------------------------------------------------------------------------
// agg16[n] = fp16( sum over incoming edges of x16[src] ), f32 accumulate.
// One wave per node, 4 gathers in flight, scalar-path csr reads.
__global__ __launch_bounds__(256) void k_agg(
    const __half* __restrict__ x16, const int* __restrict__ rowptr,
    const int* __restrict__ csr, __half* __restrict__ agg16) {
  int wid  = (blockIdx.x * blockDim.x + threadIdx.x) >> 6;
  int lane = threadIdx.x & 63;
  if (wid >= NTOT) return;
  int e0 = __builtin_amdgcn_readfirstlane(rowptr[wid]);
  int e1 = __builtin_amdgcn_readfirstlane(rowptr[wid + 1]);
  float a0 = 0.f, a1 = 0.f, a2 = 0.f, a3 = 0.f;
  int e = e0;
  for (; e + 4 <= e1; e += 4) {
    int s0 = __builtin_amdgcn_readfirstlane(csr[e]);
    int s1 = __builtin_amdgcn_readfirstlane(csr[e + 1]);
    int s2 = __builtin_amdgcn_readfirstlane(csr[e + 2]);
    int s3 = __builtin_amdgcn_readfirstlane(csr[e + 3]);
    a0 += __half2float(x16[(size_t)s0 * D + lane]);
    a1 += __half2float(x16[(size_t)s1 * D + lane]);
    a2 += __half2float(x16[(size_t)s2 * D + lane]);
    a3 += __half2float(x16[(size_t)s3 * D + lane]);
  }
  for (; e < e1; ++e) {
    int s = __builtin_amdgcn_readfirstlane(csr[e]);
    a0 += __half2float(x16[(size_t)s * D + lane]);
  }
  agg16[(size_t)wid * D + lane] = __float2half((a0 + a1) + (a2 + a3));
}

// ---------------------------------------------------------------------------
// LDS-staged dense kernels, fp16 activations, f32 weights/compute.
// A block stages a TR-row tile (uint4 per thread per array), computes from
// LDS broadcasts vs per-lane weight columns in VGPRs, double-buffered.

// hOut = leaky(agg @ conv_w); xhOut = leaky(x @ lin_w.T + lin_b)  [all fp16]
__global__ __launch_bounds__(256) void k_hx(
    const __half* __restrict__ aggIn, const __half* __restrict__ xIn,
    const float* __restrict__ convw, const float* __restrict__ linw,
    const float* __restrict__ linb,
    __half* __restrict__ hOut, __half* __restrict__ xhOut) {
  __shared__ uint4 sA[2][TR * D / 8];
  __shared__ uint4 sX[2][TR * D / 8];
  int tid  = threadIdx.x;
  int lane = tid & 63;
  int wv   = tid >> 6;
  float wc[D], wl[D];
#pragma unroll
  for (int k = 0; k < D; ++k) wc[k] = convw[k * D + lane];  // column `lane`
  const float4* lr = (const float4*)(linw + (size_t)lane * D);
#pragma unroll
  for (int k = 0; k < D / 4; ++k) {
    float4 t = lr[k];
    wl[4 * k] = t.x; wl[4 * k + 1] = t.y; wl[4 * k + 2] = t.z; wl[4 * k + 3] = t.w;
  }
  float bias = linb[lane];
  const int ntile = NTOT / TR;
  uint4 pA, pX;
  int t = blockIdx.x;
  {
    pA = ((const uint4*)(aggIn + (size_t)t * TR * D))[tid];
    pX = ((const uint4*)(xIn + (size_t)t * TR * D))[tid];
  }
  sA[0][tid] = pA; sX[0][tid] = pX;
  __syncthreads();
  int buf = 0;
  for (; t < ntile; t += gridDim.x) {
    int tn = t + gridDim.x;
    if (tn < ntile) {  // prefetch next tile into regs (overlaps compute)
      pA = ((const uint4*)(aggIn + (size_t)tn * TR * D))[tid];
      pX = ((const uint4*)(xIn + (size_t)tn * TR * D))[tid];
    }
#pragma unroll
    for (int rr = 0; rr < TR / 4; ++rr) {
      int r = wv * (TR / 4) + rr;
      const unsigned* ar = (const unsigned*)sA[buf] + r * (D / 2);
      const unsigned* xr = (const unsigned*)sX[buf] + r * (D / 2);
      float h = 0.f, xh = bias;
#pragma unroll
      for (int k = 0; k < D / 2; ++k) {
        float2 a = h2f2(ar[k]);  // uniform LDS read -> broadcast
        float2 b = h2f2(xr[k]);
        h  += a.x * wc[2 * k] + a.y * wc[2 * k + 1];
        xh += b.x * wl[2 * k] + b.y * wl[2 * k + 1];
      }
      size_t gr = (size_t)t * TR + r;
      hOut[gr * D + lane]  = __float2half(leaky(h));
      xhOut[gr * D + lane] = __float2half(leaky(xh));
    }
    __syncthreads();
    if (tn < ntile) {
      sA[buf ^ 1][tid] = pA; sX[buf ^ 1][tid] = pX;
    }
    __syncthreads();
    buf ^= 1;
  }
}

// out = (leaky?)(h @ gw[:,:64].T + xh @ gw[:,64:].T + g_b)
// out16 != nullptr -> fp16 store; else f32 store to outf.
__global__ __launch_bounds__(256) void k_g(
    const __half* __restrict__ h, const __half* __restrict__ xh,
    const float* __restrict__ gw, const float* __restrict__ gb,
    __half* __restrict__ out16, float* __restrict__ outf, int do_leaky) {
  __shared__ uint4 sH[2][TR * D / 8];
  __shared__ uint4 sX[2][TR * D / 8];
  int tid  = threadIdx.x;
  int lane = tid & 63;
  int wv   = tid >> 6;
  float whr[D], wxr[D];
  const float4* g0 = (const float4*)(gw + (size_t)lane * 2 * D);
  const float4* g1 = (const float4*)(gw + (size_t)lane * 2 * D + D);
#pragma unroll
  for (int k = 0; k < D / 4; ++k) {
    float4 t0 = g0[k];
    whr[4 * k] = t0.x; whr[4 * k + 1] = t0.y; whr[4 * k + 2] = t0.z; whr[4 * k + 3] = t0.w;
    float4 t1 = g1[k];
    wxr[4 * k] = t1.x; wxr[4 * k + 1] = t1.y; wxr[4 * k + 2] = t1.z; wxr[4 * k + 3] = t1.w;
  }
  float bias = gb[lane];
  const int ntile = NTOT / TR;
  uint4 pH, pX;
  int t = blockIdx.x;
  {
    pH = ((const uint4*)(h + (size_t)t * TR * D))[tid];
    pX = ((const uint4*)(xh + (size_t)t * TR * D))[tid];
  }
  sH[0][tid] = pH; sX[0][tid] = pX;
  __syncthreads();
  int buf = 0;
  for (; t < ntile; t += gridDim.x) {
    int tn = t + gridDim.x;
    if (tn < ntile) {
      pH = ((const uint4*)(h + (size_t)tn * TR * D))[tid];
      pX = ((const uint4*)(xh + (size_t)tn * TR * D))[tid];
    }
#pragma unroll
    for (int rr = 0; rr < TR / 4; ++rr) {
      int r = wv * (TR / 4) + rr;
      const unsigned* hr = (const unsigned*)sH[buf] + r * (D / 2);
      const unsigned* xr = (const unsigned*)sX[buf] + r * (D / 2);
      float acc = bias;
#pragma unroll
      for (int k = 0; k < D / 2; ++k) {
        float2 a = h2f2(hr[k]);
        float2 b = h2f2(xr[k]);
        acc += a.x * whr[2 * k] + a.y * whr[2 * k + 1];
        acc += b.x * wxr[2 * k] + b.y * wxr[2 * k + 1];
      }
      if (do_leaky) acc = leaky(acc);
      size_t gi = ((size_t)t * TR + r) * D + lane;
      if (out16) out16[gi] = __float2half(acc);
      else       outf[gi] = acc;
    }
    __syncthreads();
    if (tn < ntile) {
      sH[buf ^ 1][tid] = pH; sX[buf ^ 1][tid] = pX;
    }
    __syncthreads();
    buf ^= 1;
  }
}

// ---------------------------------------------------------------------------
extern "C" void kernel_launch(void* const* d_in, const int* in_sizes, int n_in,
                              void* d_out, int out_size, void* d_ws, size_t ws_size,
                              hipStream_t stream) {
  const float* features = (const float*)d_in[0];
  const int*   ei       = (const int*)d_in[1];
  const float* pref     = (const float*)d_in[2];
  const float* mlp_w    = (const float*)d_in[3];
  const float* mlp_b    = (const float*)d_in[4];
  const float* conv_w[5]; const float* lin_w[5]; const float* lin_b[5];
  const float* g_w[5];    const float* g_b[5];
  if (n_in >= 30) {
    for (int i = 0; i < 5; ++i) {
      conv_w[i] = (const float*)d_in[5 + i];
      lin_w[i]  = (const float*)d_in[10 + i];
      lin_b[i]  = (const float*)d_in[15 + i];
      g_w[i]    = (const float*)d_in[20 + i];
      g_b[i]    = (const float*)d_in[25 + i];
    }
  } else {
    const float* cw = (const float*)d_in[5];
    const float* lw = (const float*)d_in[6];
    const float* lb = (const float*)d_in[7];
    const float* gw = (const float*)d_in[8];
    const float* gb = (const float*)d_in[9];
    for (int i = 0; i < 5; ++i) {
      conv_w[i] = cw + (size_t)i * D * D;
      lin_w[i]  = lw + (size_t)i * D * D;
      lin_b[i]  = lb + (size_t)i * D;
      g_w[i]    = gw + (size_t)i * D * 2 * D;
      g_b[i]    = gb + (size_t)i * D;
    }
  }
  const int* e_src = ei;
  const int* e_dst = ei + NE;

  char* p = (char*)d_ws;
  __half* x16a  = (__half*)p; p += (size_t)NTOT * D * 2;   // 12.8 MB
  __half* x16b  = (__half*)p; p += (size_t)NTOT * D * 2;   // 12.8 MB
  __half* agg16 = (__half*)p; p += (size_t)NTOT * D * 2;   // 12.8 MB
  __half* h16   = (__half*)p; p += (size_t)NTOT * D * 2;   // 12.8 MB
  __half* xh16  = (__half*)p; p += (size_t)NTOT * D * 2;   // 12.8 MB
  int*   csr    = (int*)p;   p += (size_t)NE * 4;          // 8 MB
  int*   deg    = (int*)p;   p += (size_t)NTOT * 4;
  int*   rowptr = (int*)p;   p += (size_t)(NTOT + 4) * 4;
  int*   cursor = (int*)p;   p += (size_t)NTOT * 4;
  int*   bsum   = (int*)p;   p += 1024 * 4;
  // total ~73 MB

  float* mu     = (float*)d_out;
  float* logvar = (float*)d_out + (size_t)NTOT * D;

  const int WPB = 4;
  int grid_rows  = (NTOT + WPB - 1) / WPB;        // 25000
  int grid_edges = (NE + 255) / 256;              // 7813
  int grid_dense = 1024;                          // tile grid-stride (3125 tiles)

  k_init<<<1792, 256, 0, stream>>>(features, pref, mlp_w, mlp_b, x16a);

  // CSR by dst (rebuilt every call; deterministic work)
  k_zero<<<(NTOT + 255) / 256, 256, 0, stream>>>(deg, NTOT);
  k_hist<<<grid_edges, 256, 0, stream>>>(e_dst, deg);
  k_scan1<<<NBLK, SCANB, 0, stream>>>(deg, bsum);
  k_scan2<<<1, 512, 0, stream>>>(bsum);
  k_scan3<<<NBLK, SCANB, 0, stream>>>(deg, bsum, rowptr, cursor);
  k_scatter<<<grid_edges, 256, 0, stream>>>(e_src, e_dst, cursor, csr);

  __half* xa = x16a;
  __half* xb = x16b;
  for (int i = 0; i < 3; ++i) {
    k_agg<<<grid_rows, 256, 0, stream>>>(xa, rowptr, csr, agg16);
    k_hx<<<grid_dense, 256, 0, stream>>>(agg16, xa, conv_w[i], lin_w[i], lin_b[i], h16, xh16);
    k_g<<<grid_dense, 256, 0, stream>>>(h16, xh16, g_w[i], g_b[i], xb, nullptr, 1);
    __half* t = xa; xa = xb; xb = t;
  }

  // Heads share one aggregation of the final x.
  k_agg<<<grid_rows, 256, 0, stream>>>(xa, rowptr, csr, agg16);
  k_hx<<<grid_dense, 256, 0, stream>>>(agg16, xa, conv_w[3], lin_w[3], lin_b[3], h16, xh16);
  k_g<<<grid_dense, 256, 0, stream>>>(h16, xh16, g_w[3], g_b[3], nullptr, mu, 0);
  k_hx<<<grid_dense, 256, 0, stream>>>(agg16, xa, conv_w[4], lin_w[4], lin_b[4], h16, xh16);
  k_g<<<grid_dense, 256, 0, stream>>>(h16, xh16, g_w[4], g_b[4], nullptr, logvar, 0);
}

// Round 6
// 1110.978 us; speedup vs baseline: 2.9396x; 1.0591x over previous
//
#include <hip/hip_runtime.h>
#include <hip/hip_fp16.h>

#define DEVINL __device__ __forceinline__

constexpr int NUSER = 50000;
constexpr int NTOT  = 100000;   // NUM_USER + NUM_ITEM
constexpr int DF    = 128;
constexpr int D     = 64;
constexpr int NE    = 2000000;
constexpr int SCANB = 256;
constexpr int NBLK  = (NTOT + SCANB - 1) / SCANB;  // 391
constexpr int TR    = 32;       // dense-kernel tile rows (3125 tiles)
constexpr int NRANGE = 8;                           // dst ranges (XCD-aligned)
constexpr int RSPAN  = (NTOT + NRANGE - 1) / NRANGE;  // 12500

DEVINL float leaky(float v) { return v > 0.f ? v : 0.01f * v; }

DEVINL float2 h2f2(unsigned u) {
  __half2 h = *reinterpret_cast<__half2*>(&u);
  return __half22float2(h);
}

// ---------------------------------------------------------------------------
__global__ __launch_bounds__(256) void k_zero(int* __restrict__ p, int n) {
  int i = blockIdx.x * blockDim.x + threadIdx.x;
  if (i < n) p[i] = 0;
}

// ---------------------------------------------------------------------------
// x16[0:NUSER] = preference; rest = features @ mlp_w.T + mlp_b; row-normalize.
__global__ __launch_bounds__(256) void k_init(
    const float* __restrict__ feat, const float* __restrict__ pref,
    const float* __restrict__ mlp_w, const float* __restrict__ mlp_b,
    __half* __restrict__ x16) {
  int lane = threadIdx.x & 63;
  float wr[DF];
  const float4* wp = (const float4*)(mlp_w + (size_t)lane * DF);
#pragma unroll
  for (int k = 0; k < DF / 4; ++k) {
    float4 t = wp[k];
    wr[4 * k] = t.x; wr[4 * k + 1] = t.y; wr[4 * k + 2] = t.z; wr[4 * k + 3] = t.w;
  }
  float bias = mlp_b[lane];
  int nw = (gridDim.x * blockDim.x) >> 6;
  int w0 = (blockIdx.x * blockDim.x + threadIdx.x) >> 6;
  for (int r = w0; r < NTOT; r += nw) {
    float v;
    if (r < NUSER) {          // wave-uniform branch
      v = pref[(size_t)r * D + lane];
    } else {
      const float4* fr = (const float4*)(feat + (size_t)(r - NUSER) * DF);
      float acc = bias;
#pragma unroll
      for (int k = 0; k < DF / 4; ++k) {
        float4 a = fr[k];
        acc += a.x * wr[4 * k] + a.y * wr[4 * k + 1] + a.z * wr[4 * k + 2] + a.w * wr[4 * k + 3];
      }
      v = acc;
    }
    float ss = v * v;
#pragma unroll
    for (int o = 32; o; o >>= 1) ss += __shfl_xor(ss, o);
    float inv = 1.0f / fmaxf(sqrtf(ss), 1e-12f);
    x16[(size_t)r * D + lane] = __float2half(v * inv);
  }
}

// ---------------------------------------------------------------------------
// CSR build, dst-range-partitioned to kill inter-XCD line bouncing.
// Block b owns dst range b%8 (round-robin block->XCD mapping) and scans its
// slice of the full edge list, processing only in-range edges. Writes/atomics
// stay confined to one range's region -> accumulate in one XCD's L2.
__global__ __launch_bounds__(256) void k_hist(const int* __restrict__ dst,
                                              int* __restrict__ deg) {
  int r = blockIdx.x & (NRANGE - 1);
  int bslice = blockIdx.x >> 3;
  int nslice = gridDim.x >> 3;
  int lo = r * RSPAN, hi = lo + RSPAN;
  int per = (NE + nslice - 1) / nslice;
  int e0 = bslice * per, e1 = min(NE, e0 + per);
  for (int e = e0 + (int)threadIdx.x; e < e1; e += 256) {
    int d = dst[e];
    if (d >= lo && d < hi) atomicAdd(&deg[d], 1);
  }
}

__global__ void k_scan1(const int* __restrict__ deg, int* __restrict__ bsum) {
  __shared__ int s[SCANB];
  int i = blockIdx.x * SCANB + threadIdx.x;
  s[threadIdx.x] = (i < NTOT) ? deg[i] : 0;
  __syncthreads();
  for (int o = SCANB / 2; o; o >>= 1) {
    if (threadIdx.x < o) s[threadIdx.x] += s[threadIdx.x + o];
    __syncthreads();
  }
  if (threadIdx.x == 0) bsum[blockIdx.x] = s[0];
}

__global__ void k_scan2(int* __restrict__ bsum) {  // single block of 512
  __shared__ int s[512];
  int t = threadIdx.x;
  int v = (t < NBLK) ? bsum[t] : 0;
  s[t] = v;
  __syncthreads();
  for (int o = 1; o < 512; o <<= 1) {
    int a = (t >= o) ? s[t - o] : 0;
    __syncthreads();
    s[t] += a;
    __syncthreads();
  }
  if (t < NBLK) bsum[t] = s[t] - v;  // exclusive
}

__global__ void k_scan3(const int* __restrict__ deg, const int* __restrict__ bsum,
                        int* __restrict__ rowptr, int* __restrict__ cursor) {
  __shared__ int s[SCANB];
  int t = threadIdx.x;
  int i = blockIdx.x * SCANB + t;
  int v = (i < NTOT) ? deg[i] : 0;
  s[t] = v;
  __syncthreads();
  for (int o = 1; o < SCANB; o <<= 1) {
    int a = (t >= o) ? s[t - o] : 0;
    __syncthreads();
    s[t] += a;
    __syncthreads();
  }
  if (i < NTOT) {
    int ex = s[t] - v + bsum[blockIdx.x];
    rowptr[i] = ex;
    cursor[i] = ex;
  }
  if (i == 0) rowptr[NTOT] = NE;
}

__global__ __launch_bounds__(256) void k_scatter(
    const int* __restrict__ src, const int* __restrict__ dst,
    int* __restrict__ cursor, int* __restrict__ csr) {
  int r = blockIdx.x & (NRANGE - 1);
  int bslice = blockIdx.x >> 3;
  int nslice = gridDim.x >> 3;
  int lo = r * RSPAN, hi = lo + RSPAN;
  int per = (NE + nslice - 1) / nslice;
  int e0 = bslice * per, e1 = min(NE, e0 + per);
  for (int e = e0 + (int)threadIdx.x; e < e1; e += 256) {
    int d = dst[e];
    if (d >= lo && d < hi) {
      int p = atomicAdd(&cursor[d], 1);
      csr[p] = src[e];
    }
  }
}

// ---------------------------------------------------------------------------
// agg16[n] = fp16( sum over incoming edges of x16[src] ), f32 accumulate.
// One wave per node; lane-groups of 16 each cover a quarter row (uint2 = 4
// halves), so one load instruction gathers 4 edges; 2-deep unroll -> 8 rows
// in flight. Cross-group combine via 2 shfl_xor rounds.
__global__ __launch_bounds__(256) void k_agg(
    const __half* __restrict__ x16, const int* __restrict__ rowptr,
    const int* __restrict__ csr, __half* __restrict__ agg16) {
  int wid  = (blockIdx.x * blockDim.x + threadIdx.x) >> 6;
  int lane = threadIdx.x & 63;
  if (wid >= NTOT) return;
  int g = lane >> 4;   // edge slot 0..3
  int q = lane & 15;   // quarter-row chunk (4 halves)
  int e0 = __builtin_amdgcn_readfirstlane(rowptr[wid]);
  int e1 = __builtin_amdgcn_readfirstlane(rowptr[wid + 1]);
  float ax = 0.f, ay = 0.f, az = 0.f, aw = 0.f;
  int e = e0;
  for (; e + 8 <= e1; e += 8) {
    int sA = csr[e + g];
    int sB = csr[e + 4 + g];
    uint2 vA = ((const uint2*)(x16 + (size_t)sA * D))[q];
    uint2 vB = ((const uint2*)(x16 + (size_t)sB * D))[q];
    float2 a0 = h2f2(vA.x), a1 = h2f2(vA.y);
    float2 b0 = h2f2(vB.x), b1 = h2f2(vB.y);
    ax += a0.x + b0.x; ay += a0.y + b0.y;
    az += a1.x + b1.x; aw += a1.y + b1.y;
  }
  for (; e + 4 <= e1; e += 4) {
    int s = csr[e + g];
    uint2 v = ((const uint2*)(x16 + (size_t)s * D))[q];
    float2 l0 = h2f2(v.x), l1 = h2f2(v.y);
    ax += l0.x; ay += l0.y; az += l1.x; aw += l1.y;
  }
  int rem = e1 - e;
  if (g < rem) {
    int s = csr[e + g];
    uint2 v = ((const uint2*)(x16 + (size_t)s * D))[q];
    float2 l0 = h2f2(v.x), l1 = h2f2(v.y);
    ax += l0.x; ay += l0.y; az += l1.x; aw += l1.y;
  }
#pragma unroll
  for (int o = 16; o <= 32; o <<= 1) {
    ax += __shfl_xor(ax, o);
    ay += __shfl_xor(ay, o);
    az += __shfl_xor(az, o);
    aw += __shfl_xor(aw, o);
  }
  if (lane < 16) {
    __half2 h0 = __floats2half2_rn(ax, ay);
    __half2 h1 = __floats2half2_rn(az, aw);
    uint2 out;
    out.x = *reinterpret_cast<unsigned*>(&h0);
    out.y = *reinterpret_cast<unsigned*>(&h1);
    ((uint2*)(agg16 + (size_t)wid * D))[q] = out;
  }
}

// ---------------------------------------------------------------------------
// LDS-staged dense kernels, fp16 activations, f32 weights/compute.

// hOut = leaky(agg @ conv_w); xhOut = leaky(x @ lin_w.T + lin_b)  [all fp16]
__global__ __launch_bounds__(256) void k_hx(
    const __half* __restrict__ aggIn, const __half* __restrict__ xIn,
    const float* __restrict__ convw, const float* __restrict__ linw,
    const float* __restrict__ linb,
    __half* __restrict__ hOut, __half* __restrict__ xhOut) {
  __shared__ uint4 sA[2][TR * D / 8];
  __shared__ uint4 sX[2][TR * D / 8];
  int tid  = threadIdx.x;
  int lane = tid & 63;
  int wv   = tid >> 6;
  float wc[D], wl[D];
#pragma unroll
  for (int k = 0; k < D; ++k) wc[k] = convw[k * D + lane];  // column `lane`
  const float4* lr = (const float4*)(linw + (size_t)lane * D);
#pragma unroll
  for (int k = 0; k < D / 4; ++k) {
    float4 t = lr[k];
    wl[4 * k] = t.x; wl[4 * k + 1] = t.y; wl[4 * k + 2] = t.z; wl[4 * k + 3] = t.w;
  }
  float bias = linb[lane];
  const int ntile = NTOT / TR;
  uint4 pA, pX;
  int t = blockIdx.x;
  {
    pA = ((const uint4*)(aggIn + (size_t)t * TR * D))[tid];
    pX = ((const uint4*)(xIn + (size_t)t * TR * D))[tid];
  }
  sA[0][tid] = pA; sX[0][tid] = pX;
  __syncthreads();
  int buf = 0;
  for (; t < ntile; t += gridDim.x) {
    int tn = t + gridDim.x;
    if (tn < ntile) {  // prefetch next tile into regs (overlaps compute)
      pA = ((const uint4*)(aggIn + (size_t)tn * TR * D))[tid];
      pX = ((const uint4*)(xIn + (size_t)tn * TR * D))[tid];
    }
#pragma unroll
    for (int rr = 0; rr < TR / 4; ++rr) {
      int r = wv * (TR / 4) + rr;
      const unsigned* ar = (const unsigned*)sA[buf] + r * (D / 2);
      const unsigned* xr = (const unsigned*)sX[buf] + r * (D / 2);
      float h = 0.f, xh = bias;
#pragma unroll
      for (int k = 0; k < D / 2; ++k) {
        float2 a = h2f2(ar[k]);  // uniform LDS read -> broadcast
        float2 b = h2f2(xr[k]);
        h  += a.x * wc[2 * k] + a.y * wc[2 * k + 1];
        xh += b.x * wl[2 * k] + b.y * wl[2 * k + 1];
      }
      size_t gr = (size_t)t * TR + r;
      hOut[gr * D + lane]  = __float2half(leaky(h));
      xhOut[gr * D + lane] = __float2half(leaky(xh));
    }
    __syncthreads();
    if (tn < ntile) {
      sA[buf ^ 1][tid] = pA; sX[buf ^ 1][tid] = pX;
    }
    __syncthreads();
    buf ^= 1;
  }
}

// out = (leaky?)(h @ gw[:,:64].T + xh @ gw[:,64:].T + g_b)
__global__ __launch_bounds__(256) void k_g(
    const __half* __restrict__ h, const __half* __restrict__ xh,
    const float* __restrict__ gw, const float* __restrict__ gb,
    __half* __restrict__ out16, float* __restrict__ outf, int do_leaky) {
  __shared__ uint4 sH[2][TR * D / 8];
  __shared__ uint4 sX[2][TR * D / 8];
  int tid  = threadIdx.x;
  int lane = tid & 63;
  int wv   = tid >> 6;
  float whr[D], wxr[D];
  const float4* g0 = (const float4*)(gw + (size_t)lane * 2 * D);
  const float4* g1 = (const float4*)(gw + (size_t)lane * 2 * D + D);
#pragma unroll
  for (int k = 0; k < D / 4; ++k) {
    float4 t0 = g0[k];
    whr[4 * k] = t0.x; whr[4 * k + 1] = t0.y; whr[4 * k + 2] = t0.z; whr[4 * k + 3] = t0.w;
    float4 t1 = g1[k];
    wxr[4 * k] = t1.x; wxr[4 * k + 1] = t1.y; wxr[4 * k + 2] = t1.z; wxr[4 * k + 3] = t1.w;
  }
  float bias = gb[lane];
  const int ntile = NTOT / TR;
  uint4 pH, pX;
  int t = blockIdx.x;
  {
    pH = ((const uint4*)(h + (size_t)t * TR * D))[tid];
    pX = ((const uint4*)(xh + (size_t)t * TR * D))[tid];
  }
  sH[0][tid] = pH; sX[0][tid] = pX;
  __syncthreads();
  int buf = 0;
  for (; t < ntile; t += gridDim.x) {
    int tn = t + gridDim.x;
    if (tn < ntile) {
      pH = ((const uint4*)(h + (size_t)tn * TR * D))[tid];
      pX = ((const uint4*)(xh + (size_t)tn * TR * D))[tid];
    }
#pragma unroll
    for (int rr = 0; rr < TR / 4; ++rr) {
      int r = wv * (TR / 4) + rr;
      const unsigned* hr = (const unsigned*)sH[buf] + r * (D / 2);
      const unsigned* xr = (const unsigned*)sX[buf] + r * (D / 2);
      float acc = bias;
#pragma unroll
      for (int k = 0; k < D / 2; ++k) {
        float2 a = h2f2(hr[k]);
        float2 b = h2f2(xr[k]);
        acc += a.x * whr[2 * k] + a.y * whr[2 * k + 1];
        acc += b.x * wxr[2 * k] + b.y * wxr[2 * k + 1];
      }
      if (do_leaky) acc = leaky(acc);
      size_t gi = ((size_t)t * TR + r) * D + lane;
      if (out16) out16[gi] = __float2half(acc);
      else       outf[gi] = acc;
    }
    __syncthreads();
    if (tn < ntile) {
      sH[buf ^ 1][tid] = pH; sX[buf ^ 1][tid] = pX;
    }
    __syncthreads();
    buf ^= 1;
  }
}

// ---------------------------------------------------------------------------
extern "C" void kernel_launch(void* const* d_in, const int* in_sizes, int n_in,
                              void* d_out, int out_size, void* d_ws, size_t ws_size,
                              hipStream_t stream) {
  const float* features = (const float*)d_in[0];
  const int*   ei       = (const int*)d_in[1];
  const float* pref     = (const float*)d_in[2];
  const float* mlp_w    = (const float*)d_in[3];
  const float* mlp_b    = (const float*)d_in[4];
  const float* conv_w[5]; const float* lin_w[5]; const float* lin_b[5];
  const float* g_w[5];    const float* g_b[5];
  if (n_in >= 30) {
    for (int i = 0; i < 5; ++i) {
      conv_w[i] = (const float*)d_in[5 + i];
      lin_w[i]  = (const float*)d_in[10 + i];
      lin_b[i]  = (const float*)d_in[15 + i];
      g_w[i]    = (const float*)d_in[20 + i];
      g_b[i]    = (const float*)d_in[25 + i];
    }
  } else {
    const float* cw = (const float*)d_in[5];
    const float* lw = (const float*)d_in[6];
    const float* lb = (const float*)d_in[7];
    const float* gw = (const float*)d_in[8];
    const float* gb = (const float*)d_in[9];
    for (int i = 0; i < 5; ++i) {
      conv_w[i] = cw + (size_t)i * D * D;
      lin_w[i]  = lw + (size_t)i * D * D;
      lin_b[i]  = lb + (size_t)i * D;
      g_w[i]    = gw + (size_t)i * D * 2 * D;
      g_b[i]    = gb + (size_t)i * D;
    }
  }
  const int* e_src = ei;
  const int* e_dst = ei + NE;

  char* p = (char*)d_ws;
  __half* x16a  = (__half*)p; p += (size_t)NTOT * D * 2;   // 12.8 MB
  __half* x16b  = (__half*)p; p += (size_t)NTOT * D * 2;   // 12.8 MB
  __half* agg16 = (__half*)p; p += (size_t)NTOT * D * 2;   // 12.8 MB
  __half* h16   = (__half*)p; p += (size_t)NTOT * D * 2;   // 12.8 MB
  __half* xh16  = (__half*)p; p += (size_t)NTOT * D * 2;   // 12.8 MB
  int*   csr    = (int*)p;   p += (size_t)NE * 4;          // 8 MB
  int*   deg    = (int*)p;   p += (size_t)NTOT * 4;
  int*   rowptr = (int*)p;   p += (size_t)(NTOT + 4) * 4;
  int*   cursor = (int*)p;   p += (size_t)NTOT * 4;
  int*   bsum   = (int*)p;   p += 1024 * 4;
  // total ~73 MB

  float* mu     = (float*)d_out;
  float* logvar = (float*)d_out + (size_t)NTOT * D;

  const int WPB = 4;
  int grid_rows  = (NTOT + WPB - 1) / WPB;        // 25000
  int grid_part  = 2048;                          // range-partitioned edge kernels
  int grid_dense = 1024;                          // tile grid-stride (3125 tiles)

  k_init<<<1792, 256, 0, stream>>>(features, pref, mlp_w, mlp_b, x16a);

  // CSR by dst (rebuilt every call; deterministic work)
  k_zero<<<(NTOT + 255) / 256, 256, 0, stream>>>(deg, NTOT);
  k_hist<<<grid_part, 256, 0, stream>>>(e_dst, deg);
  k_scan1<<<NBLK, SCANB, 0, stream>>>(deg, bsum);
  k_scan2<<<1, 512, 0, stream>>>(bsum);
  k_scan3<<<NBLK, SCANB, 0, stream>>>(deg, bsum, rowptr, cursor);
  k_scatter<<<grid_part, 256, 0, stream>>>(e_src, e_dst, cursor, csr);

  __half* xa = x16a;
  __half* xb = x16b;
  for (int i = 0; i < 3; ++i) {
    k_agg<<<grid_rows, 256, 0, stream>>>(xa, rowptr, csr, agg16);
    k_hx<<<grid_dense, 256, 0, stream>>>(agg16, xa, conv_w[i], lin_w[i], lin_b[i], h16, xh16);
    k_g<<<grid_dense, 256, 0, stream>>>(h16, xh16, g_w[i], g_b[i], xb, nullptr, 1);
    __half* t = xa; xa = xb; xb = t;
  }

  // Heads share one aggregation of the final x.
  k_agg<<<grid_rows, 256, 0, stream>>>(xa, rowptr, csr, agg16);
  k_hx<<<grid_dense, 256, 0, stream>>>(agg16, xa, conv_w[3], lin_w[3], lin_b[3], h16, xh16);
  k_g<<<grid_dense, 256, 0, stream>>>(h16, xh16, g_w[3], g_b[3], nullptr, mu, 0);
  k_hx<<<grid_dense, 256, 0, stream>>>(agg16, xa, conv_w[4], lin_w[4], lin_b[4], h16, xh16);
  k_g<<<grid_dense, 256, 0, stream>>>(h16, xh16, g_w[4], g_b[4], nullptr, logvar, 0);
}

// Round 7
// 998.891 us; speedup vs baseline: 3.2695x; 1.1122x over previous
//
#include <hip/hip_runtime.h>
#include <hip/hip_fp16.h>

#define DEVINL __device__ __forceinline__

constexpr int NUSER = 50000;
constexpr int NITEM = 50000;
constexpr int NTOT  = 100000;   // NUM_USER + NUM_ITEM
constexpr int DF    = 128;
constexpr int D     = 64;
constexpr int NE    = 2000000;
constexpr int SCANB = 256;
constexpr int NBLK  = (NTOT + SCANB - 1) / SCANB;  // 391
constexpr int TR    = 32;       // tile rows
constexpr int NRANGE = 8;                           // dst ranges (XCD-aligned)
constexpr int RSPAN  = (NTOT + NRANGE - 1) / NRANGE;  // 12500

DEVINL float leaky(float v) { return v > 0.f ? v : 0.01f * v; }

DEVINL float2 h2f2(unsigned u) {
  __half2 h = *reinterpret_cast<__half2*>(&u);
  return __half22float2(h);
}

// ---------------------------------------------------------------------------
__global__ __launch_bounds__(256) void k_zero(int* __restrict__ p, int n) {
  int i = blockIdx.x * blockDim.x + threadIdx.x;
  if (i < n) p[i] = 0;
}

// ---------------------------------------------------------------------------
// User half of init: x16[r] = normalize(pref[r]). One wave per row.
__global__ __launch_bounds__(256) void k_init_user(
    const float* __restrict__ pref, __half* __restrict__ x16) {
  int wid  = (blockIdx.x * blockDim.x + threadIdx.x) >> 6;
  int lane = threadIdx.x & 63;
  if (wid >= NUSER) return;
  float v = pref[(size_t)wid * D + lane];
  float ss = v * v;
#pragma unroll
  for (int o = 32; o; o >>= 1) ss += __shfl_xor(ss, o);
  float inv = 1.0f / fmaxf(sqrtf(ss), 1e-12f);
  x16[(size_t)wid * D + lane] = __float2half(v * inv);
}

// Item half: x16[NUSER+r] = normalize(feat[r] @ mlp_w.T + mlp_b).
// 512 threads = 8 waves: (row-group 0..3) x (k-half 0..1). Each lane holds
// 64 weight floats (no spill). Feature tile staged coalesced in LDS;
// partials combined through LDS, then row-normalize + fp16 store.
__global__ __launch_bounds__(512) void k_init_item(
    const float* __restrict__ feat, const float* __restrict__ mlp_w,
    const float* __restrict__ mlp_b, __half* __restrict__ x16) {
  __shared__ float sF[TR * DF];        // 16 KB feature tile
  __shared__ float sP[2][TR][D];       // 16 KB partial sums (per k-half)
  int tid  = threadIdx.x;
  int lane = tid & 63;
  int wv   = tid >> 6;     // 0..7
  int kh   = wv & 1;       // k-half
  int rg   = wv >> 1;      // row group 0..3
  float wh[D];
  const float4* wp = (const float4*)(mlp_w + (size_t)lane * DF + kh * D);
#pragma unroll
  for (int k = 0; k < D / 4; ++k) {
    float4 t = wp[k];
    wh[4 * k] = t.x; wh[4 * k + 1] = t.y; wh[4 * k + 2] = t.z; wh[4 * k + 3] = t.w;
  }
  float bias = mlp_b[lane];
  int t = blockIdx.x;
  // stage tile t (1024 float4 slots, 2 per thread), zero-pad past NITEM
  {
    const float4* base = (const float4*)(feat + (size_t)t * TR * DF);
    float4* dstl = (float4*)sF;
#pragma unroll
    for (int s = 0; s < 2; ++s) {
      int slot = tid + s * 512;
      int gr = t * TR + (slot >> 5);
      float4 v = make_float4(0.f, 0.f, 0.f, 0.f);
      if (gr < NITEM) v = base[slot];
      dstl[slot] = v;
    }
  }
  __syncthreads();
  // partial dot over this wave's k-half for its 8 rows
#pragma unroll
  for (int rr = 0; rr < 8; ++rr) {
    int r = rg * 8 + rr;
    const float4* fr = (const float4*)&sF[r * DF + kh * D];
    float acc = 0.f;
#pragma unroll
    for (int k = 0; k < D / 4; ++k) {
      float4 a = fr[k];   // uniform LDS read -> broadcast
      acc += a.x * wh[4 * k] + a.y * wh[4 * k + 1] + a.z * wh[4 * k + 2] + a.w * wh[4 * k + 3];
    }
    sP[kh][r][lane] = acc;
  }
  __syncthreads();
  // combine halves + bias, normalize, store fp16 (4 rows per wave)
#pragma unroll
  for (int rr = 0; rr < 4; ++rr) {
    int r = wv * 4 + rr;
    int gr = t * TR + r;
    float v = sP[0][r][lane] + sP[1][r][lane] + bias;
    float ss = v * v;
#pragma unroll
    for (int o = 32; o; o >>= 1) ss += __shfl_xor(ss, o);
    float inv = 1.0f / fmaxf(sqrtf(ss), 1e-12f);
    if (gr < NITEM) x16[(size_t)(NUSER + gr) * D + lane] = __float2half(v * inv);
  }
}

// ---------------------------------------------------------------------------
// CSR build, dst-range-partitioned to kill inter-XCD line bouncing.
__global__ __launch_bounds__(256) void k_hist(const int* __restrict__ dst,
                                              int* __restrict__ deg) {
  int r = blockIdx.x & (NRANGE - 1);
  int bslice = blockIdx.x >> 3;
  int nslice = gridDim.x >> 3;
  int lo = r * RSPAN, hi = lo + RSPAN;
  int per = (NE + nslice - 1) / nslice;
  int e0 = bslice * per, e1 = min(NE, e0 + per);
  for (int e = e0 + (int)threadIdx.x; e < e1; e += 256) {
    int d = dst[e];
    if (d >= lo && d < hi) atomicAdd(&deg[d], 1);
  }
}

__global__ void k_scan1(const int* __restrict__ deg, int* __restrict__ bsum) {
  __shared__ int s[SCANB];
  int i = blockIdx.x * SCANB + threadIdx.x;
  s[threadIdx.x] = (i < NTOT) ? deg[i] : 0;
  __syncthreads();
  for (int o = SCANB / 2; o; o >>= 1) {
    if (threadIdx.x < o) s[threadIdx.x] += s[threadIdx.x + o];
    __syncthreads();
  }
  if (threadIdx.x == 0) bsum[blockIdx.x] = s[0];
}

__global__ void k_scan2(int* __restrict__ bsum) {  // single block of 512
  __shared__ int s[512];
  int t = threadIdx.x;
  int v = (t < NBLK) ? bsum[t] : 0;
  s[t] = v;
  __syncthreads();
  for (int o = 1; o < 512; o <<= 1) {
    int a = (t >= o) ? s[t - o] : 0;
    __syncthreads();
    s[t] += a;
    __syncthreads();
  }
  if (t < NBLK) bsum[t] = s[t] - v;  // exclusive
}

__global__ void k_scan3(const int* __restrict__ deg, const int* __restrict__ bsum,
                        int* __restrict__ rowptr, int* __restrict__ cursor) {
  __shared__ int s[SCANB];
  int t = threadIdx.x;
  int i = blockIdx.x * SCANB + t;
  int v = (i < NTOT) ? deg[i] : 0;
  s[t] = v;
  __syncthreads();
  for (int o = 1; o < SCANB; o <<= 1) {
    int a = (t >= o) ? s[t - o] : 0;
    __syncthreads();
    s[t] += a;
    __syncthreads();
  }
  if (i < NTOT) {
    int ex = s[t] - v + bsum[blockIdx.x];
    rowptr[i] = ex;
    cursor[i] = ex;
  }
  if (i == 0) rowptr[NTOT] = NE;
}

__global__ __launch_bounds__(256) void k_scatter(
    const int* __restrict__ src, const int* __restrict__ dst,
    int* __restrict__ cursor, int* __restrict__ csr) {
  int r = blockIdx.x & (NRANGE - 1);
  int bslice = blockIdx.x >> 3;
  int nslice = gridDim.x >> 3;
  int lo = r * RSPAN, hi = lo + RSPAN;
  int per = (NE + nslice - 1) / nslice;
  int e0 = bslice * per, e1 = min(NE, e0 + per);
  for (int e = e0 + (int)threadIdx.x; e < e1; e += 256) {
    int d = dst[e];
    if (d >= lo && d < hi) {
      int p = atomicAdd(&cursor[d], 1);
      csr[p] = src[e];
    }
  }
}

// ---------------------------------------------------------------------------
// agg16[n] = fp16( sum over incoming edges of x16[src] ), f32 accumulate.
// One wave per node; 8-lane groups (g=lane>>3) each cover 1/8 row via uint4
// (16B = 8 halves), so one load instruction gathers 8 edges; 2-deep unroll
// -> 16 rows in flight. Cross-group combine via 3 shfl_xor rounds.
__global__ __launch_bounds__(256) void k_agg(
    const __half* __restrict__ x16, const int* __restrict__ rowptr,
    const int* __restrict__ csr, __half* __restrict__ agg16) {
  int wid  = (blockIdx.x * blockDim.x + threadIdx.x) >> 6;
  int lane = threadIdx.x & 63;
  if (wid >= NTOT) return;
  int g = lane >> 3;   // edge slot 0..7
  int q = lane & 7;    // 1/8-row chunk (uint4 = 8 halves)
  int e0 = __builtin_amdgcn_readfirstlane(rowptr[wid]);
  int e1 = __builtin_amdgcn_readfirstlane(rowptr[wid + 1]);
  float a[8] = {0.f, 0.f, 0.f, 0.f, 0.f, 0.f, 0.f, 0.f};
  int e = e0;
  for (; e + 16 <= e1; e += 16) {
    int sA = csr[e + g];
    int sB = csr[e + 8 + g];
    uint4 vA = ((const uint4*)(x16 + (size_t)sA * D))[q];
    uint4 vB = ((const uint4*)(x16 + (size_t)sB * D))[q];
    float2 t;
    t = h2f2(vA.x); a[0] += t.x; a[1] += t.y;
    t = h2f2(vA.y); a[2] += t.x; a[3] += t.y;
    t = h2f2(vA.z); a[4] += t.x; a[5] += t.y;
    t = h2f2(vA.w); a[6] += t.x; a[7] += t.y;
    t = h2f2(vB.x); a[0] += t.x; a[1] += t.y;
    t = h2f2(vB.y); a[2] += t.x; a[3] += t.y;
    t = h2f2(vB.z); a[4] += t.x; a[5] += t.y;
    t = h2f2(vB.w); a[6] += t.x; a[7] += t.y;
  }
  for (; e + 8 <= e1; e += 8) {
    int s = csr[e + g];
    uint4 v = ((const uint4*)(x16 + (size_t)s * D))[q];
    float2 t;
    t = h2f2(v.x); a[0] += t.x; a[1] += t.y;
    t = h2f2(v.y); a[2] += t.x; a[3] += t.y;
    t = h2f2(v.z); a[4] += t.x; a[5] += t.y;
    t = h2f2(v.w); a[6] += t.x; a[7] += t.y;
  }
  int rem = e1 - e;
  if (g < rem) {
    int s = csr[e + g];
    uint4 v = ((const uint4*)(x16 + (size_t)s * D))[q];
    float2 t;
    t = h2f2(v.x); a[0] += t.x; a[1] += t.y;
    t = h2f2(v.y); a[2] += t.x; a[3] += t.y;
    t = h2f2(v.z); a[4] += t.x; a[5] += t.y;
    t = h2f2(v.w); a[6] += t.x; a[7] += t.y;
  }
#pragma unroll
  for (int o = 8; o <= 32; o <<= 1) {
#pragma unroll
    for (int i = 0; i < 8; ++i) a[i] += __shfl_xor(a[i], o);
  }
  if (lane < 8) {
    __half2 h0 = __floats2half2_rn(a[0], a[1]);
    __half2 h1 = __floats2half2_rn(a[2], a[3]);
    __half2 h2 = __floats2half2_rn(a[4], a[5]);
    __half2 h3 = __floats2half2_rn(a[6], a[7]);
    uint4 out;
    out.x = *reinterpret_cast<unsigned*>(&h0);
    out.y = *reinterpret_cast<unsigned*>(&h1);
    out.z = *reinterpret_cast<unsigned*>(&h2);
    out.w = *reinterpret_cast<unsigned*>(&h3);
    ((uint4*)(agg16 + (size_t)wid * D))[q] = out;
  }
}

// ---------------------------------------------------------------------------
// LDS-staged dense kernels, fp16 activations, f32 weights/compute.

// hOut = leaky(agg @ conv_w); xhOut = leaky(x @ lin_w.T + lin_b)  [all fp16]
__global__ __launch_bounds__(256) void k_hx(
    const __half* __restrict__ aggIn, const __half* __restrict__ xIn,
    const float* __restrict__ convw, const float* __restrict__ linw,
    const float* __restrict__ linb,
    __half* __restrict__ hOut, __half* __restrict__ xhOut) {
  __shared__ uint4 sA[2][TR * D / 8];
  __shared__ uint4 sX[2][TR * D / 8];
  int tid  = threadIdx.x;
  int lane = tid & 63;
  int wv   = tid >> 6;
  float wc[D], wl[D];
#pragma unroll
  for (int k = 0; k < D; ++k) wc[k] = convw[k * D + lane];  // column `lane`
  const float4* lr = (const float4*)(linw + (size_t)lane * D);
#pragma unroll
  for (int k = 0; k < D / 4; ++k) {
    float4 t = lr[k];
    wl[4 * k] = t.x; wl[4 * k + 1] = t.y; wl[4 * k + 2] = t.z; wl[4 * k + 3] = t.w;
  }
  float bias = linb[lane];
  const int ntile = NTOT / TR;
  uint4 pA, pX;
  int t = blockIdx.x;
  {
    pA = ((const uint4*)(aggIn + (size_t)t * TR * D))[tid];
    pX = ((const uint4*)(xIn + (size_t)t * TR * D))[tid];
  }
  sA[0][tid] = pA; sX[0][tid] = pX;
  __syncthreads();
  int buf = 0;
  for (; t < ntile; t += gridDim.x) {
    int tn = t + gridDim.x;
    if (tn < ntile) {  // prefetch next tile into regs (overlaps compute)
      pA = ((const uint4*)(aggIn + (size_t)tn * TR * D))[tid];
      pX = ((const uint4*)(xIn + (size_t)tn * TR * D))[tid];
    }
#pragma unroll
    for (int rr = 0; rr < TR / 4; ++rr) {
      int r = wv * (TR / 4) + rr;
      const unsigned* ar = (const unsigned*)sA[buf] + r * (D / 2);
      const unsigned* xr = (const unsigned*)sX[buf] + r * (D / 2);
      float h = 0.f, xh = bias;
#pragma unroll
      for (int k = 0; k < D / 2; ++k) {
        float2 a = h2f2(ar[k]);  // uniform LDS read -> broadcast
        float2 b = h2f2(xr[k]);
        h  += a.x * wc[2 * k] + a.y * wc[2 * k + 1];
        xh += b.x * wl[2 * k] + b.y * wl[2 * k + 1];
      }
      size_t gr = (size_t)t * TR + r;
      hOut[gr * D + lane]  = __float2half(leaky(h));
      xhOut[gr * D + lane] = __float2half(leaky(xh));
    }
    __syncthreads();
    if (tn < ntile) {
      sA[buf ^ 1][tid] = pA; sX[buf ^ 1][tid] = pX;
    }
    __syncthreads();
    buf ^= 1;
  }
}

// out = (leaky?)(h @ gw[:,:64].T + xh @ gw[:,64:].T + g_b)
__global__ __launch_bounds__(256) void k_g(
    const __half* __restrict__ h, const __half* __restrict__ xh,
    const float* __restrict__ gw, const float* __restrict__ gb,
    __half* __restrict__ out16, float* __restrict__ outf, int do_leaky) {
  __shared__ uint4 sH[2][TR * D / 8];
  __shared__ uint4 sX[2][TR * D / 8];
  int tid  = threadIdx.x;
  int lane = tid & 63;
  int wv   = tid >> 6;
  float whr[D], wxr[D];
  const float4* g0 = (const float4*)(gw + (size_t)lane * 2 * D);
  const float4* g1 = (const float4*)(gw + (size_t)lane * 2 * D + D);
#pragma unroll
  for (int k = 0; k < D / 4; ++k) {
    float4 t0 = g0[k];
    whr[4 * k] = t0.x; whr[4 * k + 1] = t0.y; whr[4 * k + 2] = t0.z; whr[4 * k + 3] = t0.w;
    float4 t1 = g1[k];
    wxr[4 * k] = t1.x; wxr[4 * k + 1] = t1.y; wxr[4 * k + 2] = t1.z; wxr[4 * k + 3] = t1.w;
  }
  float bias = gb[lane];
  const int ntile = NTOT / TR;
  uint4 pH, pX;
  int t = blockIdx.x;
  {
    pH = ((const uint4*)(h + (size_t)t * TR * D))[tid];
    pX = ((const uint4*)(xh + (size_t)t * TR * D))[tid];
  }
  sH[0][tid] = pH; sX[0][tid] = pX;
  __syncthreads();
  int buf = 0;
  for (; t < ntile; t += gridDim.x) {
    int tn = t + gridDim.x;
    if (tn < ntile) {
      pH = ((const uint4*)(h + (size_t)tn * TR * D))[tid];
      pX = ((const uint4*)(xh + (size_t)tn * TR * D))[tid];
    }
#pragma unroll
    for (int rr = 0; rr < TR / 4; ++rr) {
      int r = wv * (TR / 4) + rr;
      const unsigned* hr = (const unsigned*)sH[buf] + r * (D / 2);
      const unsigned* xr = (const unsigned*)sX[buf] + r * (D / 2);
      float acc = bias;
#pragma unroll
      for (int k = 0; k < D / 2; ++k) {
        float2 a = h2f2(hr[k]);
        float2 b = h2f2(xr[k]);
        acc += a.x * whr[2 * k] + a.y * whr[2 * k + 1];
        acc += b.x * wxr[2 * k] + b.y * wxr[2 * k + 1];
      }
      if (do_leaky) acc = leaky(acc);
      size_t gi = ((size_t)t * TR + r) * D + lane;
      if (out16) out16[gi] = __float2half(acc);
      else       outf[gi] = acc;
    }
    __syncthreads();
    if (tn < ntile) {
      sH[buf ^ 1][tid] = pH; sX[buf ^ 1][tid] = pX;
    }
    __syncthreads();
    buf ^= 1;
  }
}

// ---------------------------------------------------------------------------
extern "C" void kernel_launch(void* const* d_in, const int* in_sizes, int n_in,
                              void* d_out, int out_size, void* d_ws, size_t ws_size,
                              hipStream_t stream) {
  const float* features = (const float*)d_in[0];
  const int*   ei       = (const int*)d_in[1];
  const float* pref     = (const float*)d_in[2];
  const float* mlp_w    = (const float*)d_in[3];
  const float* mlp_b    = (const float*)d_in[4];
  const float* conv_w[5]; const float* lin_w[5]; const float* lin_b[5];
  const float* g_w[5];    const float* g_b[5];
  if (n_in >= 30) {
    for (int i = 0; i < 5; ++i) {
      conv_w[i] = (const float*)d_in[5 + i];
      lin_w[i]  = (const float*)d_in[10 + i];
      lin_b[i]  = (const float*)d_in[15 + i];
      g_w[i]    = (const float*)d_in[20 + i];
      g_b[i]    = (const float*)d_in[25 + i];
    }
  } else {
    const float* cw = (const float*)d_in[5];
    const float* lw = (const float*)d_in[6];
    const float* lb = (const float*)d_in[7];
    const float* gw = (const float*)d_in[8];
    const float* gb = (const float*)d_in[9];
    for (int i = 0; i < 5; ++i) {
      conv_w[i] = cw + (size_t)i * D * D;
      lin_w[i]  = lw + (size_t)i * D * D;
      lin_b[i]  = lb + (size_t)i * D;
      g_w[i]    = gw + (size_t)i * D * 2 * D;
      g_b[i]    = gb + (size_t)i * D;
    }
  }
  const int* e_src = ei;
  const int* e_dst = ei + NE;

  char* p = (char*)d_ws;
  __half* x16a  = (__half*)p; p += (size_t)NTOT * D * 2;   // 12.8 MB
  __half* x16b  = (__half*)p; p += (size_t)NTOT * D * 2;   // 12.8 MB
  __half* agg16 = (__half*)p; p += (size_t)NTOT * D * 2;   // 12.8 MB
  __half* h16   = (__half*)p; p += (size_t)NTOT * D * 2;   // 12.8 MB
  __half* xh16  = (__half*)p; p += (size_t)NTOT * D * 2;   // 12.8 MB
  int*   csr    = (int*)p;   p += (size_t)NE * 4;          // 8 MB
  int*   deg    = (int*)p;   p += (size_t)NTOT * 4;
  int*   rowptr = (int*)p;   p += (size_t)(NTOT + 4) * 4;
  int*   cursor = (int*)p;   p += (size_t)NTOT * 4;
  int*   bsum   = (int*)p;   p += 1024 * 4;
  // total ~73 MB

  float* mu     = (float*)d_out;
  float* logvar = (float*)d_out + (size_t)NTOT * D;

  const int WPB = 4;
  int grid_rows  = (NTOT + WPB - 1) / WPB;        // 25000
  int grid_part  = 2048;                          // range-partitioned edge kernels
  int grid_dense = 1024;                          // tile grid-stride (3125 tiles)
  int ntile_item = (NITEM + TR - 1) / TR;         // 1563

  k_init_user<<<(NUSER + 3) / 4, 256, 0, stream>>>(pref, x16a);
  k_init_item<<<ntile_item, 512, 0, stream>>>(features, mlp_w, mlp_b, x16a);

  // CSR by dst (rebuilt every call; deterministic work)
  k_zero<<<(NTOT + 255) / 256, 256, 0, stream>>>(deg, NTOT);
  k_hist<<<grid_part, 256, 0, stream>>>(e_dst, deg);
  k_scan1<<<NBLK, SCANB, 0, stream>>>(deg, bsum);
  k_scan2<<<1, 512, 0, stream>>>(bsum);
  k_scan3<<<NBLK, SCANB, 0, stream>>>(deg, bsum, rowptr, cursor);
  k_scatter<<<grid_part, 256, 0, stream>>>(e_src, e_dst, cursor, csr);

  __half* xa = x16a;
  __half* xb = x16b;
  for (int i = 0; i < 3; ++i) {
    k_agg<<<grid_rows, 256, 0, stream>>>(xa, rowptr, csr, agg16);
    k_hx<<<grid_dense, 256, 0, stream>>>(agg16, xa, conv_w[i], lin_w[i], lin_b[i], h16, xh16);
    k_g<<<grid_dense, 256, 0, stream>>>(h16, xh16, g_w[i], g_b[i], xb, nullptr, 1);
    __half* t = xa; xa = xb; xb = t;
  }

  // Heads share one aggregation of the final x.
  k_agg<<<grid_rows, 256, 0, stream>>>(xa, rowptr, csr, agg16);
  k_hx<<<grid_dense, 256, 0, stream>>>(agg16, xa, conv_w[3], lin_w[3], lin_b[3], h16, xh16);
  k_g<<<grid_dense, 256, 0, stream>>>(h16, xh16, g_w[3], g_b[3], nullptr, mu, 0);
  k_hx<<<grid_dense, 256, 0, stream>>>(agg16, xa, conv_w[4], lin_w[4], lin_b[4], h16, xh16);
  k_g<<<grid_dense, 256, 0, stream>>>(h16, xh16, g_w[4], g_b[4], nullptr, logvar, 0);
}